// Round 8
// baseline (2616.596 us; speedup 1.0000x reference)
//
#include <hip/hip_runtime.h>

typedef unsigned short u16;
using f16x8 = __attribute__((ext_vector_type(8))) _Float16;  // 8 fp16 (4 VGPRs)
using f32x4 = __attribute__((ext_vector_type(4))) float;

#define V_N 16384
#define M_N 32768

__device__ __forceinline__ float h2f(u16 u) {
  _Float16 h; __builtin_memcpy(&h, &u, 2); return (float)h;
}
__device__ __forceinline__ u16 f2h(float f) {
  _Float16 h = (_Float16)f; u16 u; __builtin_memcpy(&u, &h, 2); return u;
}

// ---------- prep kernels ----------
// LDS-transpose weight permute: wp[o][t*256+c] = f2h(w[o][c*12+t])
__global__ __launch_bounds__(256) void perm2_k(const float* __restrict__ w, u16* __restrict__ wp) {
  __shared__ u16 l[3072];
  int o = blockIdx.x & 255, layer = blockIdx.x >> 8;
  int t = threadIdx.x;
  const float* src = w + ((size_t)layer * 256 + o) * 3072;
  u16* dst = wp + ((size_t)layer * 256 + o) * 3072;
  float2 v[6];
  #pragma unroll
  for (int q = 0; q < 6; ++q) v[q] = *(const float2*)(src + t * 12 + q * 2);
  const float* vf = (const float*)v;
  #pragma unroll
  for (int m = 0; m < 12; ++m) l[m * 256 + t] = f2h(vf[m]);   // c = t
  __syncthreads();
  unsigned* d32 = (unsigned*)dst;
  const unsigned* l32 = (const unsigned*)l;
  #pragma unroll
  for (int q = 0; q < 6; ++q) d32[t * 6 + q] = l32[t * 6 + q];
}

// flat f32 -> fp16 convert
__global__ __launch_bounds__(256) void cvt_k(const float* __restrict__ w, u16* __restrict__ wb, int n) {
  int i = blockIdx.x * 256 + threadIdx.x;
  if (i < n) wb[i] = f2h(w[i]);
}

// ---------- encoder block 0 conv (C_in=3, K=36), f32 in -> fp16 out ----------
__global__ __launch_bounds__(256) void enc0_k(const float* __restrict__ verts, const int* __restrict__ sp,
                                              const float* __restrict__ w0, u16* __restrict__ y) {
  __shared__ float xs[32][36];
  int t = threadIdx.x;
  int r0 = blockIdx.x * 32;
  for (int s = t; s < 32 * 12; s += 256) {
    int row = s / 12, tt = s - row * 12;
    int gr = r0 + row;
    int b = gr >> 14, v = gr & (V_N - 1);
    int j = sp[tt * V_N + v];
    const float* p = verts + ((long)b * V_N + j) * 3;
    xs[row][tt]      = p[0];
    xs[row][12 + tt] = p[1];
    xs[row][24 + tt] = p[2];
  }
  __syncthreads();
  float w[36];
  #pragma unroll
  for (int k = 0; k < 36; ++k) w[k] = w0[t * 36 + k];
  for (int row = 0; row < 32; ++row) {
    float a = 0.f;
    #pragma unroll
    for (int k = 0; k < 36; ++k) a += w[k] * xs[row][k];
    y[(long)(r0 + row) * 256 + t] = f2h(a);
  }
}

// ---------- staged MFMA GEMM: 64M x 256N tile, 512 thr (8 waves of 32M x 64N) ----------
// Y[M x Ostore](fp16) = gatherA[M x (L*CT)] * Wt^T (+f32 bias) (+fused BN stats).
// Gather: row = b*V + sp[l*V+v]; dense: row = bm+srow, P0 (l==0) / P1 (l>=1).
// Staging scale: scl0 -> scale all l by scl0[b][c]; else scl1 -> scale l>=1 by scl1[b][c].
// LDS 32KB (CT=256): 2 blocks/CU -> 16 waves/CU, two independent barrier groups.
template<int CT>
__global__ __launch_bounds__(512, 4) void gemm2_k(
    const u16* __restrict__ P0, const u16* __restrict__ P1, int lda,
    const int* __restrict__ sp, int L,
    const u16* __restrict__ Wt, int ldw,
    const float* __restrict__ scl0, const float* __restrict__ scl1,
    u16* __restrict__ Yb, const float* __restrict__ bias, int Ostore,
    float* __restrict__ stats)
{
  constexpr int KC  = CT >> 5;     // K-chunks of 32 per tap (8 for CT=256, 4 for CT=128)
  constexpr int SPT = CT >> 6;     // 16B segs staged per thread (4 / 2)
  __shared__ __align__(16) u16 lA[64 * CT];
  const int tid  = threadIdx.x;
  const int wave = tid >> 6, lane = tid & 63;
  const int wm = (wave & 1) * 32, wn = (wave >> 1) * 64;
  const int lr = lane & 15, lq = lane >> 4;
  const int bm = blockIdx.x * 64;
  const int batch = bm >> 14;
  const int srow = tid >> 3, slot = tid & 7;    // 64 rows x 8 slots
  const bool gat = (sp != nullptr);
  const int TK = L * KC;

  // staging scale vector (per-thread fixed channel set)
  f16x8 sg[SPT];
  const float* sclA = scl0 ? scl0 : scl1;
  if (sclA) {
    #pragma unroll
    for (int j = 0; j < SPT; ++j) {
      const float* s = sclA + batch * 256 + (slot * SPT + j) * 8;
      f16x8 tv;
      #pragma unroll
      for (int e = 0; e < 8; ++e) tv[e] = (_Float16)s[e];
      sg[j] = tv;
    }
  }

  // B fragment pointers
  const u16* bp[4];
  #pragma unroll
  for (int nt = 0; nt < 4; ++nt) bp[nt] = Wt + (long)(wn + nt * 16 + lr) * ldw + lq * 8;

  // ---- prologue: stage l=0 row into regs, prefetch idx, B gs=0,1 ----
  const long rowbase = gat ? ((long)batch * V_N * lda) : 0;
  const int vloc = (bm & (V_N - 1)) + srow;
  f16x8 r[SPT];
  {
    const u16* b0;
    if (gat) b0 = P0 + rowbase + (long)sp[vloc] * lda;
    else     b0 = P0 + (long)(bm + srow) * lda;
    #pragma unroll
    for (int j = 0; j < SPT; ++j) r[j] = *(const f16x8*)(b0 + (slot * SPT + j) * 8);
  }
  int idx_nxt = (gat && L > 1) ? sp[V_N + vloc] : 0;

  f16x8 bv0[4], bv1[4];
  #pragma unroll
  for (int nt = 0; nt < 4; ++nt) bv0[nt] = *(const f16x8*)(bp[nt]);
  #pragma unroll
  for (int nt = 0; nt < 4; ++nt) bv1[nt] = *(const f16x8*)(bp[nt] + 32);

  f32x4 acc[2][4];
  #pragma unroll
  for (int i = 0; i < 2; ++i)
    #pragma unroll
    for (int j = 0; j < 4; ++j) acc[i][j] = (f32x4){0.f, 0.f, 0.f, 0.f};

  for (int l = 0; l < L; ++l) {
    __syncthreads();                       // previous-l LDS consumers done
    const bool scale_now = (scl0 != nullptr) || (scl1 != nullptr && l >= 1);
    #pragma unroll
    for (int j = 0; j < SPT; ++j) {
      f16x8 rv = r[j];
      if (scale_now) rv = rv * sg[j];
      int ss = ((slot * SPT + j) ^ (srow & 7)) * 8;
      *(f16x8*)(&lA[srow * CT + ss]) = rv;
    }
    __syncthreads();                       // LDS ready
    // issue next-l staging AFTER the barrier (full MFMA phase to complete)
    if (l + 1 < L) {
      const u16* nb;
      if (gat) nb = P0 + rowbase + (long)idx_nxt * lda;
      else { const u16* Pn = P1 ? P1 : P0; nb = Pn + (long)(bm + srow) * lda; }
      #pragma unroll
      for (int j = 0; j < SPT; ++j) r[j] = *(const f16x8*)(nb + (slot * SPT + j) * 8);
      if (gat && l + 2 < L) idx_nxt = sp[(long)(l + 2) * V_N + vloc];
    }
    // A-frag + B depth-2 ping-pong, all names compile-time
    f16x8 a0[2], a1[2];
    #pragma unroll
    for (int mt = 0; mt < 2; ++mt) {
      int row = wm + mt * 16 + lr;
      a0[mt] = *(const f16x8*)(&lA[row * CT + ((lq ^ (row & 7)) * 8)]);
    }
    #pragma unroll
    for (int kc = 0; kc < KC; kc += 2) {
      const int gs = l * KC + kc;
      #pragma unroll
      for (int mt = 0; mt < 2; ++mt) {
        int row = wm + mt * 16 + lr;
        a1[mt] = *(const f16x8*)(&lA[row * CT + ((((kc + 1) * 4 + lq) ^ (row & 7)) * 8)]);
      }
      f16x8 t0[4];
      if (gs + 2 < TK) {
        #pragma unroll
        for (int nt = 0; nt < 4; ++nt) t0[nt] = *(const f16x8*)(bp[nt] + (long)(gs + 2) * 32);
      }
      #pragma unroll
      for (int mt = 0; mt < 2; ++mt)
        #pragma unroll
        for (int nt = 0; nt < 4; ++nt)
          acc[mt][nt] = __builtin_amdgcn_mfma_f32_16x16x32_f16(a0[mt], bv0[nt], acc[mt][nt], 0, 0, 0);
      if (kc + 2 < KC) {
        #pragma unroll
        for (int mt = 0; mt < 2; ++mt) {
          int row = wm + mt * 16 + lr;
          a0[mt] = *(const f16x8*)(&lA[row * CT + ((((kc + 2) * 4 + lq) ^ (row & 7)) * 8)]);
        }
      }
      f16x8 t1[4];
      if (gs + 3 < TK) {
        #pragma unroll
        for (int nt = 0; nt < 4; ++nt) t1[nt] = *(const f16x8*)(bp[nt] + (long)(gs + 3) * 32);
      }
      #pragma unroll
      for (int mt = 0; mt < 2; ++mt)
        #pragma unroll
        for (int nt = 0; nt < 4; ++nt)
          acc[mt][nt] = __builtin_amdgcn_mfma_f32_16x16x32_f16(a1[mt], bv1[nt], acc[mt][nt], 0, 0, 0);
      #pragma unroll
      for (int nt = 0; nt < 4; ++nt) { bv0[nt] = t0[nt]; bv1[nt] = t1[nt]; }
    }
  }

  // epilogue: C/D layout col=lane&15, row=(lane>>4)*4+reg [guide m89]; fused stats
  #pragma unroll
  for (int nt = 0; nt < 4; ++nt) {
    int col = wn + nt * 16 + lr;
    if (col < Ostore) {
      float bv = bias ? bias[col] : 0.f;
      float s1 = 0.f, s2 = 0.f;
      #pragma unroll
      for (int mt = 0; mt < 2; ++mt) {
        #pragma unroll
        for (int rg = 0; rg < 4; ++rg) {
          int row = bm + wm + mt * 16 + lq * 4 + rg;
          float v = acc[mt][nt][rg] + bv;
          Yb[(long)row * Ostore + col] = f2h(v);
          s1 += v; s2 += v * v;
        }
      }
      if (stats) {
        s1 += __shfl_xor(s1, 16); s1 += __shfl_xor(s1, 32);
        s2 += __shfl_xor(s2, 16); s2 += __shfl_xor(s2, 32);
        if (lq == 0) {
          atomicAdd(&stats[col], s1);
          atomicAdd(&stats[Ostore + col], s2);
        }
      }
    }
  }
}

// ---------- stats for enc0 output (O=256), vectorized ----------
__global__ __launch_bounds__(256) void stats2_k(const u16* __restrict__ y, float* __restrict__ st) {
  __shared__ float s1L[256], s2L[256];
  int tid = threadIdx.x;
  int ci = (tid & 63) * 4;
  int r0 = blockIdx.x * 64 + (tid >> 6);
  float a1[4] = {0,0,0,0}, a2[4] = {0,0,0,0};
  for (int it = 0; it < 16; ++it) {
    long i = ((long)r0 + it * 4) * 256 + ci;
    uint2 pv = *(const uint2*)(y + i);
    float v0 = h2f((u16)(pv.x & 0xffff)), v1 = h2f((u16)(pv.x >> 16));
    float v2 = h2f((u16)(pv.y & 0xffff)), v3 = h2f((u16)(pv.y >> 16));
    a1[0] += v0; a1[1] += v1; a1[2] += v2; a1[3] += v3;
    a2[0] += v0*v0; a2[1] += v1*v1; a2[2] += v2*v2; a2[3] += v3*v3;
  }
  s1L[tid] = 0.f; s2L[tid] = 0.f;
  __syncthreads();
  #pragma unroll
  for (int j = 0; j < 4; ++j) { atomicAdd(&s1L[ci + j], a1[j]); atomicAdd(&s2L[ci + j], a2[j]); }
  __syncthreads();
  atomicAdd(&st[tid], s1L[tid]);
  atomicAdd(&st[256 + tid], s2L[tid]);
}

// ---------- vectorized BN+ReLU (+fp16 residual, optional per-channel resid scale) (+SE sums) ----------
__global__ __launch_bounds__(256) void bnrelu2_k(
    const u16* __restrict__ y, const float* __restrict__ st,
    const float* __restrict__ g, const float* __restrict__ be,
    const u16* __restrict__ resid, const float* __restrict__ rscale,
    u16* __restrict__ ob, float* __restrict__ ses, int O)
{
  __shared__ float sL[256];
  int tid = threadIdx.x;
  int tpr = O >> 2;
  int rpi = 256 / tpr;
  int ci = (tid & (tpr - 1)) * 4;
  int row0 = blockIdx.x * (rpi * 16);
  int r0 = row0 + (tid / tpr);
  int b = row0 >> 14;
  float mean[4], sc[4], sh[4], rs[4];
  #pragma unroll
  for (int j = 0; j < 4; ++j) {
    int c = ci + j;
    float m = st[c] * (1.f / 32768.f);
    float var = st[O + c] * (1.f / 32768.f) - m * m;
    mean[j] = m;
    sc[j] = rsqrtf(fmaxf(var, 0.f) + 1e-5f) * g[c];
    sh[j] = be[c];
    rs[j] = rscale ? rscale[b * 256 + c] : 1.f;
  }
  float ss[4] = {0,0,0,0};
  for (int it = 0; it < 16; ++it) {
    long i = ((long)r0 + (long)it * rpi) * O + ci;
    uint2 pv = *(const uint2*)(y + i);
    float v[4];
    v[0] = fmaxf((h2f((u16)(pv.x & 0xffff)) - mean[0]) * sc[0] + sh[0], 0.f);
    v[1] = fmaxf((h2f((u16)(pv.x >> 16))    - mean[1]) * sc[1] + sh[1], 0.f);
    v[2] = fmaxf((h2f((u16)(pv.y & 0xffff)) - mean[2]) * sc[2] + sh[2], 0.f);
    v[3] = fmaxf((h2f((u16)(pv.y >> 16))    - mean[3]) * sc[3] + sh[3], 0.f);
    if (resid) {
      uint2 rv = *(const uint2*)(resid + i);
      v[0] += h2f((u16)(rv.x & 0xffff)) * rs[0]; v[1] += h2f((u16)(rv.x >> 16)) * rs[1];
      v[2] += h2f((u16)(rv.y & 0xffff)) * rs[2]; v[3] += h2f((u16)(rv.y >> 16)) * rs[3];
    }
    uint2 pk;
    pk.x = (unsigned)f2h(v[0]) | ((unsigned)f2h(v[1]) << 16);
    pk.y = (unsigned)f2h(v[2]) | ((unsigned)f2h(v[3]) << 16);
    *(uint2*)(ob + i) = pk;
    #pragma unroll
    for (int j = 0; j < 4; ++j) ss[j] += v[j];
  }
  if (ses) {
    sL[tid] = 0.f;
    __syncthreads();
    #pragma unroll
    for (int j = 0; j < 4; ++j) atomicAdd(&sL[ci + j], ss[j]);
    __syncthreads();
    atomicAdd(&ses[b * O + tid], sL[tid]);
  }
}

// ---------- SE gate ----------
__global__ void se_k(const float* __restrict__ ses, const float* __restrict__ w1,
                     const float* __restrict__ w2, float* __restrict__ sig)
{
  __shared__ float s[256];
  __shared__ float h[32];
  int b = blockIdx.x, t = threadIdx.x;
  s[t] = ses[b * 256 + t] * (1.f / 16384.f);
  __syncthreads();
  if (t < 32) {
    float a = 0.f;
    for (int c = 0; c < 256; ++c) a += w1[t * 256 + c] * s[c];
    h[t] = fmaxf(a, 0.f);
  }
  __syncthreads();
  float a = 0.f;
  #pragma unroll
  for (int r = 0; r < 32; ++r) a += w2[t * 32 + r] * h[r];
  sig[b * 256 + t] = 1.f / (1.f + expf(-a));
}

// ---------- x = out * sig (single use: decoder input materialization) ----------
__global__ __launch_bounds__(256) void scale_k(const u16* __restrict__ t, const float* __restrict__ sig,
                                               u16* __restrict__ xb)
{
  long i = ((long)blockIdx.x * 256 + threadIdx.x) * 4;
  int b = (int)(i >> 22);
  int c = (int)(i & 255);
  uint2 pv = *(const uint2*)(t + i);
  const float* sgp = sig + b * 256 + c;
  float v0 = h2f((u16)(pv.x & 0xffff)) * sgp[0];
  float v1 = h2f((u16)(pv.x >> 16))    * sgp[1];
  float v2 = h2f((u16)(pv.y & 0xffff)) * sgp[2];
  float v3 = h2f((u16)(pv.y >> 16))    * sgp[3];
  uint2 pk;
  pk.x = (unsigned)f2h(v0) | ((unsigned)f2h(v1) << 16);
  pk.y = (unsigned)f2h(v2) | ((unsigned)f2h(v3) << 16);
  *(uint2*)(xb + i) = pk;
}

// ---------- final head ----------
__global__ __launch_bounds__(256) void cls3_k(const u16* __restrict__ h2, const float* __restrict__ w,
                                              const float* __restrict__ b, float* __restrict__ out)
{
  __shared__ float ws[64];
  int t = threadIdx.x;
  if (t < 64) ws[t] = w[t];
  __syncthreads();
  int r = blockIdx.x * 256 + t;
  const u16* p = h2 + (long)r * 64;
  float a = b[0];
  #pragma unroll
  for (int c = 0; c < 64; ++c) a += ws[c] * h2f(p[c]);
  out[r] = a;
}

extern "C" void kernel_launch(void* const* d_in, const int* in_sizes, int n_in,
                              void* d_out, int out_size, void* d_ws, size_t ws_size,
                              hipStream_t stream)
{
  (void)in_sizes; (void)n_in; (void)out_size; (void)ws_size;
  const float* verts   = (const float*)d_in[0];
  const int*   spirals = (const int*)d_in[1];
  const float* enc0_w  = (const float*)d_in[2];
  const float* enc0_g  = (const float*)d_in[4];
  const float* enc0_be = (const float*)d_in[5];
  const float* enc_w   = (const float*)d_in[6];
  const float* enc_g   = (const float*)d_in[8];
  const float* enc_be  = (const float*)d_in[9];
  const float* se_w1   = (const float*)d_in[10];
  const float* se_w2   = (const float*)d_in[11];
  const float* skip_w  = (const float*)d_in[12];
  const float* skip_b  = (const float*)d_in[13];
  const float* dec_w   = (const float*)d_in[14];
  const float* dec_g   = (const float*)d_in[16];
  const float* dec_be  = (const float*)d_in[17];
  const float* cls1_w  = (const float*)d_in[18];
  const float* cls1_g  = (const float*)d_in[20];
  const float* cls1_be = (const float*)d_in[21];
  const float* cls2_w  = (const float*)d_in[22];
  const float* cls2_g  = (const float*)d_in[24];
  const float* cls2_be = (const float*)d_in[25];
  const float* cls3_w  = (const float*)d_in[26];
  const float* cls3_b  = (const float*)d_in[27];

  // --- workspace (~107 MB) ---
  char* p = (char*)d_ws;
  auto alloc = [&](size_t n) { char* q = p; p += (n + 255) & ~(size_t)255; return q; };
  u16* wpe   = (u16*)alloc((size_t)6 * 256 * 3072 * 2);
  u16* skip_wb = (u16*)alloc((size_t)3 * 256 * 512 * 2);
  u16* cls1_wb = (u16*)alloc((size_t)256 * 256 * 2);   // zero-padded to 256 rows
  u16* wp6     = (u16*)alloc((size_t)256 * 128 * 2);   // zero-padded to 256 rows
  float* stats = (float*)alloc(2048);
  float* sesum = (float*)alloc(2048);                  // contiguous after stats
  float* sig   = (float*)alloc(4 * 2048);              // sig_i = sig + i*512
  u16* out0 = (u16*)alloc((size_t)M_N * 256 * 2);
  u16* out1 = (u16*)alloc((size_t)M_N * 256 * 2);
  u16* out2 = (u16*)alloc((size_t)M_N * 256 * 2);
  u16* ct   = (u16*)alloc((size_t)M_N * 256 * 2);      // conv temp; aliases out3
  u16* tb   = (u16*)alloc((size_t)M_N * 256 * 2);
  u16* xd   = (u16*)alloc((size_t)M_N * 256 * 2);
  u16* outs[4] = {out0, out1, out2, ct};

  // prep
  perm2_k<<<768, 256, 0, stream>>>(enc_w, wpe);
  perm2_k<<<768, 256, 0, stream>>>(dec_w, wpe + (size_t)3 * 256 * 3072);
  cvt_k<<<1536, 256, 0, stream>>>(skip_w, skip_wb, 3 * 256 * 512);
  hipMemsetAsync(cls1_wb, 0, 256 * 256 * 2, stream);
  cvt_k<<<128, 256, 0, stream>>>(cls1_w, cls1_wb, 128 * 256);
  hipMemsetAsync(wp6, 0, 256 * 128 * 2, stream);
  cvt_k<<<32, 256, 0, stream>>>(cls2_w, wp6, 64 * 128);

  // ---- encoder block 0 ----
  hipMemsetAsync(stats, 0, 4096, stream);
  enc0_k<<<1024, 256, 0, stream>>>(verts, spirals, enc0_w, ct);
  stats2_k<<<512, 256, 0, stream>>>(ct, stats);
  bnrelu2_k<<<512, 256, 0, stream>>>(ct, stats, enc0_g, enc0_be, nullptr, nullptr, out0, sesum, 256);
  se_k<<<2, 256, 0, stream>>>(sesum, se_w1, se_w2, sig);

  // ---- encoder blocks 1..3 (x_{i-1} = out_{i-1} * sig_{i-1}, fused into staging/resid) ----
  for (int i = 1; i < 4; ++i) {
    hipMemsetAsync(stats, 0, 4096, stream);
    gemm2_k<256><<<512, 512, 0, stream>>>(outs[i - 1], nullptr, 256,
                                          spirals + (size_t)i * V_N * 12, 12,
                                          wpe + (size_t)(i - 1) * 256 * 3072, 3072,
                                          sig + (i - 1) * 512, nullptr,
                                          ct, nullptr, 256, stats);
    bnrelu2_k<<<512, 256, 0, stream>>>(ct, stats, enc_g + (i - 1) * 256, enc_be + (i - 1) * 256,
                                       outs[i - 1], sig + (i - 1) * 512, outs[i], sesum, 256);
    se_k<<<2, 256, 0, stream>>>(sesum, se_w1 + (size_t)i * 32 * 256,
                                se_w2 + (size_t)i * 256 * 32, sig + i * 512);
  }

  // decoder input x = out3 * sig3 (materialized once; out3 aliases ct)
  scale_k<<<8192, 256, 0, stream>>>(ct, sig + 3 * 512, xd);

  // ---- decoder blocks ----
  for (int i = 0; i < 3; ++i) {
    gemm2_k<256><<<512, 512, 0, stream>>>(xd, outs[2 - i], 256, nullptr, 2,
                                          skip_wb + (size_t)i * 256 * 512, 512,
                                          nullptr, sig + (2 - i) * 512,
                                          tb, skip_b + i * 256, 256, nullptr);       // x1 -> tb
    hipMemsetAsync(stats, 0, 4096, stream);
    gemm2_k<256><<<512, 512, 0, stream>>>(tb, nullptr, 256,
                                          spirals + (size_t)(2 - i) * V_N * 12, 12,
                                          wpe + (size_t)(3 + i) * 256 * 3072, 3072,
                                          nullptr, nullptr,
                                          outs[2 - i], nullptr, 256, stats);          // conv -> out[2-i]
    bnrelu2_k<<<512, 256, 0, stream>>>(outs[2 - i], stats, dec_g + i * 256, dec_be + i * 256,
                                       tb, nullptr, xd, nullptr, 256);                // x -> xd
  }

  // ---- classifier ----
  hipMemsetAsync(stats, 0, 4096, stream);
  gemm2_k<256><<<512, 512, 0, stream>>>(xd, nullptr, 256, nullptr, 1,
                                        cls1_wb, 256, nullptr, nullptr, ct, nullptr, 128, stats);
  bnrelu2_k<<<256, 256, 0, stream>>>(ct, stats, cls1_g, cls1_be, nullptr, nullptr, ct, nullptr, 128);
  hipMemsetAsync(stats, 0, 4096, stream);
  gemm2_k<128><<<512, 512, 0, stream>>>(ct, nullptr, 128, nullptr, 1,
                                        wp6, 128, nullptr, nullptr, tb, nullptr, 64, stats);
  bnrelu2_k<<<128, 256, 0, stream>>>(tb, stats, cls2_g, cls2_be, nullptr, nullptr, tb, nullptr, 64);
  cls3_k<<<128, 256, 0, stream>>>(tb, cls3_w, cls3_b, (float*)d_out);
}

// Round 9
// 1899.023 us; speedup vs baseline: 1.3779x; 1.3779x over previous
//
#include <hip/hip_runtime.h>

typedef unsigned short u16;
using f16x8 = __attribute__((ext_vector_type(8))) _Float16;  // 8 fp16 (4 VGPRs)
using f32x4 = __attribute__((ext_vector_type(4))) float;

#define V_N 16384
#define M_N 32768

__device__ __forceinline__ float h2f(u16 u) {
  _Float16 h; __builtin_memcpy(&h, &u, 2); return (float)h;
}
__device__ __forceinline__ u16 f2h(float f) {
  _Float16 h = (_Float16)f; u16 u; __builtin_memcpy(&u, &h, 2); return u;
}

// ---------- prep kernels ----------
// LDS-transpose weight permute: wp[o][t*256+c] = f2h(w[o][c*12+t])
__global__ __launch_bounds__(256) void perm2_k(const float* __restrict__ w, u16* __restrict__ wp) {
  __shared__ u16 l[3072];
  int o = blockIdx.x & 255, layer = blockIdx.x >> 8;
  int t = threadIdx.x;
  const float* src = w + ((size_t)layer * 256 + o) * 3072;
  u16* dst = wp + ((size_t)layer * 256 + o) * 3072;
  float2 v[6];
  #pragma unroll
  for (int q = 0; q < 6; ++q) v[q] = *(const float2*)(src + t * 12 + q * 2);
  const float* vf = (const float*)v;
  #pragma unroll
  for (int m = 0; m < 12; ++m) l[m * 256 + t] = f2h(vf[m]);   // c = t
  __syncthreads();
  unsigned* d32 = (unsigned*)dst;
  const unsigned* l32 = (const unsigned*)l;
  #pragma unroll
  for (int q = 0; q < 6; ++q) d32[t * 6 + q] = l32[t * 6 + q];
}

// flat f32 -> fp16 convert
__global__ __launch_bounds__(256) void cvt_k(const float* __restrict__ w, u16* __restrict__ wb, int n) {
  int i = blockIdx.x * 256 + threadIdx.x;
  if (i < n) wb[i] = f2h(w[i]);
}

// ---------- encoder block 0 conv (C_in=3, K=36), f32 in -> fp16 out ----------
__global__ __launch_bounds__(256) void enc0_k(const float* __restrict__ verts, const int* __restrict__ sp,
                                              const float* __restrict__ w0, u16* __restrict__ y) {
  __shared__ float xs[32][36];
  int t = threadIdx.x;
  int r0 = blockIdx.x * 32;
  for (int s = t; s < 32 * 12; s += 256) {
    int row = s / 12, tt = s - row * 12;
    int gr = r0 + row;
    int b = gr >> 14, v = gr & (V_N - 1);
    int j = sp[tt * V_N + v];
    const float* p = verts + ((long)b * V_N + j) * 3;
    xs[row][tt]      = p[0];
    xs[row][12 + tt] = p[1];
    xs[row][24 + tt] = p[2];
  }
  __syncthreads();
  float w[36];
  #pragma unroll
  for (int k = 0; k < 36; ++k) w[k] = w0[t * 36 + k];
  for (int row = 0; row < 32; ++row) {
    float a = 0.f;
    #pragma unroll
    for (int k = 0; k < 36; ++k) a += w[k] * xs[row][k];
    y[(long)(r0 + row) * 256 + t] = f2h(a);
  }
}

// ---------- staged MFMA GEMM: 64M x 256N tile, 512 thr (8 waves of 32M x 64N) ----------
// Y[M x Ostore](fp16) = gatherA[M x (L*CT)] * Wt^T (+f32 bias) (+fused BN stats).
// Gather: row = b*V + sp[l*V+v]; dense: row = bm+srow, P0 (l==0) / P1 (l>=1).
// Staging scale: scl0 -> scale all l by scl0[b][c]; else scl1 -> scale l>=1 by scl1[b][c].
// LDS 32KB; no forced min-waves (R8's ",4" forced VGPR=64 -> spill; let allocator pick ~128).
template<int CT>
__global__ __launch_bounds__(512) void gemm2_k(
    const u16* __restrict__ P0, const u16* __restrict__ P1, int lda,
    const int* __restrict__ sp, int L,
    const u16* __restrict__ Wt, int ldw,
    const float* __restrict__ scl0, const float* __restrict__ scl1,
    u16* __restrict__ Yb, const float* __restrict__ bias, int Ostore,
    float* __restrict__ stats)
{
  constexpr int KC  = CT >> 5;     // K-chunks of 32 per tap (8 for CT=256, 4 for CT=128)
  constexpr int SPT = CT >> 6;     // 16B segs staged per thread (4 / 2)
  __shared__ __align__(16) u16 lA[64 * CT];
  const int tid  = threadIdx.x;
  const int wave = tid >> 6, lane = tid & 63;
  const int wm = (wave & 1) * 32, wn = (wave >> 1) * 64;
  const int lr = lane & 15, lq = lane >> 4;
  const int bm = blockIdx.x * 64;
  const int batch = bm >> 14;
  const int srow = tid >> 3, slot = tid & 7;    // 64 rows x 8 slots
  const bool gat = (sp != nullptr);
  const int TK = L * KC;

  // staging scale vector (per-thread fixed channel set)
  f16x8 sg[SPT];
  const float* sclA = scl0 ? scl0 : scl1;
  if (sclA) {
    #pragma unroll
    for (int j = 0; j < SPT; ++j) {
      const float* s = sclA + batch * 256 + (slot * SPT + j) * 8;
      f16x8 tv;
      #pragma unroll
      for (int e = 0; e < 8; ++e) tv[e] = (_Float16)s[e];
      sg[j] = tv;
    }
  }

  // B fragment pointers
  const u16* bp[4];
  #pragma unroll
  for (int nt = 0; nt < 4; ++nt) bp[nt] = Wt + (long)(wn + nt * 16 + lr) * ldw + lq * 8;

  // ---- prologue: stage l=0 row into regs, prefetch idx, B gs=0,1 ----
  const long rowbase = gat ? ((long)batch * V_N * lda) : 0;
  const int vloc = (bm & (V_N - 1)) + srow;
  f16x8 r[SPT];
  {
    const u16* b0;
    if (gat) b0 = P0 + rowbase + (long)sp[vloc] * lda;
    else     b0 = P0 + (long)(bm + srow) * lda;
    #pragma unroll
    for (int j = 0; j < SPT; ++j) r[j] = *(const f16x8*)(b0 + (slot * SPT + j) * 8);
  }
  int idx_nxt = (gat && L > 1) ? sp[V_N + vloc] : 0;

  f16x8 bv0[4], bv1[4];
  #pragma unroll
  for (int nt = 0; nt < 4; ++nt) bv0[nt] = *(const f16x8*)(bp[nt]);
  #pragma unroll
  for (int nt = 0; nt < 4; ++nt) bv1[nt] = *(const f16x8*)(bp[nt] + 32);

  f32x4 acc[2][4];
  #pragma unroll
  for (int i = 0; i < 2; ++i)
    #pragma unroll
    for (int j = 0; j < 4; ++j) acc[i][j] = (f32x4){0.f, 0.f, 0.f, 0.f};

  for (int l = 0; l < L; ++l) {
    __syncthreads();                       // previous-l LDS consumers done
    const bool scale_now = (scl0 != nullptr) || (scl1 != nullptr && l >= 1);
    #pragma unroll
    for (int j = 0; j < SPT; ++j) {
      f16x8 rv = r[j];
      if (scale_now) rv = rv * sg[j];
      int ss = ((slot * SPT + j) ^ (srow & 7)) * 8;
      *(f16x8*)(&lA[srow * CT + ss]) = rv;
    }
    __syncthreads();                       // LDS ready
    // issue next-l staging AFTER the barrier (full MFMA phase to complete)
    if (l + 1 < L) {
      const u16* nb;
      if (gat) nb = P0 + rowbase + (long)idx_nxt * lda;
      else { const u16* Pn = P1 ? P1 : P0; nb = Pn + (long)(bm + srow) * lda; }
      #pragma unroll
      for (int j = 0; j < SPT; ++j) r[j] = *(const f16x8*)(nb + (slot * SPT + j) * 8);
      if (gat && l + 2 < L) idx_nxt = sp[(long)(l + 2) * V_N + vloc];
    }
    // A-frag + B depth-2 ping-pong, all names compile-time
    f16x8 a0[2], a1[2];
    #pragma unroll
    for (int mt = 0; mt < 2; ++mt) {
      int row = wm + mt * 16 + lr;
      a0[mt] = *(const f16x8*)(&lA[row * CT + ((lq ^ (row & 7)) * 8)]);
    }
    #pragma unroll
    for (int kc = 0; kc < KC; kc += 2) {
      const int gs = l * KC + kc;
      #pragma unroll
      for (int mt = 0; mt < 2; ++mt) {
        int row = wm + mt * 16 + lr;
        a1[mt] = *(const f16x8*)(&lA[row * CT + ((((kc + 1) * 4 + lq) ^ (row & 7)) * 8)]);
      }
      f16x8 t0[4];
      if (gs + 2 < TK) {
        #pragma unroll
        for (int nt = 0; nt < 4; ++nt) t0[nt] = *(const f16x8*)(bp[nt] + (long)(gs + 2) * 32);
      }
      #pragma unroll
      for (int mt = 0; mt < 2; ++mt)
        #pragma unroll
        for (int nt = 0; nt < 4; ++nt)
          acc[mt][nt] = __builtin_amdgcn_mfma_f32_16x16x32_f16(a0[mt], bv0[nt], acc[mt][nt], 0, 0, 0);
      if (kc + 2 < KC) {
        #pragma unroll
        for (int mt = 0; mt < 2; ++mt) {
          int row = wm + mt * 16 + lr;
          a0[mt] = *(const f16x8*)(&lA[row * CT + ((((kc + 2) * 4 + lq) ^ (row & 7)) * 8)]);
        }
      }
      f16x8 t1[4];
      if (gs + 3 < TK) {
        #pragma unroll
        for (int nt = 0; nt < 4; ++nt) t1[nt] = *(const f16x8*)(bp[nt] + (long)(gs + 3) * 32);
      }
      #pragma unroll
      for (int mt = 0; mt < 2; ++mt)
        #pragma unroll
        for (int nt = 0; nt < 4; ++nt)
          acc[mt][nt] = __builtin_amdgcn_mfma_f32_16x16x32_f16(a1[mt], bv1[nt], acc[mt][nt], 0, 0, 0);
      #pragma unroll
      for (int nt = 0; nt < 4; ++nt) { bv0[nt] = t0[nt]; bv1[nt] = t1[nt]; }
    }
  }

  // epilogue: C/D layout col=lane&15, row=(lane>>4)*4+reg [guide m89]; fused stats
  #pragma unroll
  for (int nt = 0; nt < 4; ++nt) {
    int col = wn + nt * 16 + lr;
    if (col < Ostore) {
      float bv = bias ? bias[col] : 0.f;
      float s1 = 0.f, s2 = 0.f;
      #pragma unroll
      for (int mt = 0; mt < 2; ++mt) {
        #pragma unroll
        for (int rg = 0; rg < 4; ++rg) {
          int row = bm + wm + mt * 16 + lq * 4 + rg;
          float v = acc[mt][nt][rg] + bv;
          Yb[(long)row * Ostore + col] = f2h(v);
          s1 += v; s2 += v * v;
        }
      }
      if (stats) {
        s1 += __shfl_xor(s1, 16); s1 += __shfl_xor(s1, 32);
        s2 += __shfl_xor(s2, 16); s2 += __shfl_xor(s2, 32);
        if (lq == 0) {
          atomicAdd(&stats[col], s1);
          atomicAdd(&stats[Ostore + col], s2);
        }
      }
    }
  }
}

// ---------- stats for enc0 output (O=256), vectorized ----------
__global__ __launch_bounds__(256) void stats2_k(const u16* __restrict__ y, float* __restrict__ st) {
  __shared__ float s1L[256], s2L[256];
  int tid = threadIdx.x;
  int ci = (tid & 63) * 4;
  int r0 = blockIdx.x * 64 + (tid >> 6);
  float a1[4] = {0,0,0,0}, a2[4] = {0,0,0,0};
  for (int it = 0; it < 16; ++it) {
    long i = ((long)r0 + it * 4) * 256 + ci;
    uint2 pv = *(const uint2*)(y + i);
    float v0 = h2f((u16)(pv.x & 0xffff)), v1 = h2f((u16)(pv.x >> 16));
    float v2 = h2f((u16)(pv.y & 0xffff)), v3 = h2f((u16)(pv.y >> 16));
    a1[0] += v0; a1[1] += v1; a1[2] += v2; a1[3] += v3;
    a2[0] += v0*v0; a2[1] += v1*v1; a2[2] += v2*v2; a2[3] += v3*v3;
  }
  s1L[tid] = 0.f; s2L[tid] = 0.f;
  __syncthreads();
  #pragma unroll
  for (int j = 0; j < 4; ++j) { atomicAdd(&s1L[ci + j], a1[j]); atomicAdd(&s2L[ci + j], a2[j]); }
  __syncthreads();
  atomicAdd(&st[tid], s1L[tid]);
  atomicAdd(&st[256 + tid], s2L[tid]);
}

// ---------- vectorized BN+ReLU (+fp16 residual, optional per-channel resid scale) (+SE sums) ----------
__global__ __launch_bounds__(256) void bnrelu2_k(
    const u16* __restrict__ y, const float* __restrict__ st,
    const float* __restrict__ g, const float* __restrict__ be,
    const u16* __restrict__ resid, const float* __restrict__ rscale,
    u16* __restrict__ ob, float* __restrict__ ses, int O)
{
  __shared__ float sL[256];
  int tid = threadIdx.x;
  int tpr = O >> 2;
  int rpi = 256 / tpr;
  int ci = (tid & (tpr - 1)) * 4;
  int row0 = blockIdx.x * (rpi * 16);
  int r0 = row0 + (tid / tpr);
  int b = row0 >> 14;
  float mean[4], sc[4], sh[4], rs[4];
  #pragma unroll
  for (int j = 0; j < 4; ++j) {
    int c = ci + j;
    float m = st[c] * (1.f / 32768.f);
    float var = st[O + c] * (1.f / 32768.f) - m * m;
    mean[j] = m;
    sc[j] = rsqrtf(fmaxf(var, 0.f) + 1e-5f) * g[c];
    sh[j] = be[c];
    rs[j] = rscale ? rscale[b * 256 + c] : 1.f;
  }
  float ss[4] = {0,0,0,0};
  for (int it = 0; it < 16; ++it) {
    long i = ((long)r0 + (long)it * rpi) * O + ci;
    uint2 pv = *(const uint2*)(y + i);
    float v[4];
    v[0] = fmaxf((h2f((u16)(pv.x & 0xffff)) - mean[0]) * sc[0] + sh[0], 0.f);
    v[1] = fmaxf((h2f((u16)(pv.x >> 16))    - mean[1]) * sc[1] + sh[1], 0.f);
    v[2] = fmaxf((h2f((u16)(pv.y & 0xffff)) - mean[2]) * sc[2] + sh[2], 0.f);
    v[3] = fmaxf((h2f((u16)(pv.y >> 16))    - mean[3]) * sc[3] + sh[3], 0.f);
    if (resid) {
      uint2 rv = *(const uint2*)(resid + i);
      v[0] += h2f((u16)(rv.x & 0xffff)) * rs[0]; v[1] += h2f((u16)(rv.x >> 16)) * rs[1];
      v[2] += h2f((u16)(rv.y & 0xffff)) * rs[2]; v[3] += h2f((u16)(rv.y >> 16)) * rs[3];
    }
    uint2 pk;
    pk.x = (unsigned)f2h(v[0]) | ((unsigned)f2h(v[1]) << 16);
    pk.y = (unsigned)f2h(v[2]) | ((unsigned)f2h(v[3]) << 16);
    *(uint2*)(ob + i) = pk;
    #pragma unroll
    for (int j = 0; j < 4; ++j) ss[j] += v[j];
  }
  if (ses) {
    sL[tid] = 0.f;
    __syncthreads();
    #pragma unroll
    for (int j = 0; j < 4; ++j) atomicAdd(&sL[ci + j], ss[j]);
    __syncthreads();
    atomicAdd(&ses[b * O + tid], sL[tid]);
  }
}

// ---------- SE gate ----------
__global__ void se_k(const float* __restrict__ ses, const float* __restrict__ w1,
                     const float* __restrict__ w2, float* __restrict__ sig)
{
  __shared__ float s[256];
  __shared__ float h[32];
  int b = blockIdx.x, t = threadIdx.x;
  s[t] = ses[b * 256 + t] * (1.f / 16384.f);
  __syncthreads();
  if (t < 32) {
    float a = 0.f;
    for (int c = 0; c < 256; ++c) a += w1[t * 256 + c] * s[c];
    h[t] = fmaxf(a, 0.f);
  }
  __syncthreads();
  float a = 0.f;
  #pragma unroll
  for (int r = 0; r < 32; ++r) a += w2[t * 32 + r] * h[r];
  sig[b * 256 + t] = 1.f / (1.f + expf(-a));
}

// ---------- x = out * sig (single use: decoder input materialization) ----------
__global__ __launch_bounds__(256) void scale_k(const u16* __restrict__ t, const float* __restrict__ sig,
                                               u16* __restrict__ xb)
{
  long i = ((long)blockIdx.x * 256 + threadIdx.x) * 4;
  int b = (int)(i >> 22);
  int c = (int)(i & 255);
  uint2 pv = *(const uint2*)(t + i);
  const float* sgp = sig + b * 256 + c;
  float v0 = h2f((u16)(pv.x & 0xffff)) * sgp[0];
  float v1 = h2f((u16)(pv.x >> 16))    * sgp[1];
  float v2 = h2f((u16)(pv.y & 0xffff)) * sgp[2];
  float v3 = h2f((u16)(pv.y >> 16))    * sgp[3];
  uint2 pk;
  pk.x = (unsigned)f2h(v0) | ((unsigned)f2h(v1) << 16);
  pk.y = (unsigned)f2h(v2) | ((unsigned)f2h(v3) << 16);
  *(uint2*)(xb + i) = pk;
}

// ---------- final head ----------
__global__ __launch_bounds__(256) void cls3_k(const u16* __restrict__ h2, const float* __restrict__ w,
                                              const float* __restrict__ b, float* __restrict__ out)
{
  __shared__ float ws[64];
  int t = threadIdx.x;
  if (t < 64) ws[t] = w[t];
  __syncthreads();
  int r = blockIdx.x * 256 + t;
  const u16* p = h2 + (long)r * 64;
  float a = b[0];
  #pragma unroll
  for (int c = 0; c < 64; ++c) a += ws[c] * h2f(p[c]);
  out[r] = a;
}

extern "C" void kernel_launch(void* const* d_in, const int* in_sizes, int n_in,
                              void* d_out, int out_size, void* d_ws, size_t ws_size,
                              hipStream_t stream)
{
  (void)in_sizes; (void)n_in; (void)out_size; (void)ws_size;
  const float* verts   = (const float*)d_in[0];
  const int*   spirals = (const int*)d_in[1];
  const float* enc0_w  = (const float*)d_in[2];
  const float* enc0_g  = (const float*)d_in[4];
  const float* enc0_be = (const float*)d_in[5];
  const float* enc_w   = (const float*)d_in[6];
  const float* enc_g   = (const float*)d_in[8];
  const float* enc_be  = (const float*)d_in[9];
  const float* se_w1   = (const float*)d_in[10];
  const float* se_w2   = (const float*)d_in[11];
  const float* skip_w  = (const float*)d_in[12];
  const float* skip_b  = (const float*)d_in[13];
  const float* dec_w   = (const float*)d_in[14];
  const float* dec_g   = (const float*)d_in[16];
  const float* dec_be  = (const float*)d_in[17];
  const float* cls1_w  = (const float*)d_in[18];
  const float* cls1_g  = (const float*)d_in[20];
  const float* cls1_be = (const float*)d_in[21];
  const float* cls2_w  = (const float*)d_in[22];
  const float* cls2_g  = (const float*)d_in[24];
  const float* cls2_be = (const float*)d_in[25];
  const float* cls3_w  = (const float*)d_in[26];
  const float* cls3_b  = (const float*)d_in[27];

  // --- workspace (~107 MB) ---
  char* p = (char*)d_ws;
  auto alloc = [&](size_t n) { char* q = p; p += (n + 255) & ~(size_t)255; return q; };
  u16* wpe   = (u16*)alloc((size_t)6 * 256 * 3072 * 2);
  u16* skip_wb = (u16*)alloc((size_t)3 * 256 * 512 * 2);
  u16* cls1_wb = (u16*)alloc((size_t)256 * 256 * 2);   // zero-padded to 256 rows
  u16* wp6     = (u16*)alloc((size_t)256 * 128 * 2);   // zero-padded to 256 rows
  float* stats = (float*)alloc(2048);
  float* sesum = (float*)alloc(2048);                  // contiguous after stats
  float* sig   = (float*)alloc(4 * 2048);              // sig_i = sig + i*512
  u16* out0 = (u16*)alloc((size_t)M_N * 256 * 2);
  u16* out1 = (u16*)alloc((size_t)M_N * 256 * 2);
  u16* out2 = (u16*)alloc((size_t)M_N * 256 * 2);
  u16* ct   = (u16*)alloc((size_t)M_N * 256 * 2);      // conv temp; aliases out3
  u16* tb   = (u16*)alloc((size_t)M_N * 256 * 2);
  u16* xd   = (u16*)alloc((size_t)M_N * 256 * 2);
  u16* outs[4] = {out0, out1, out2, ct};

  // prep
  perm2_k<<<768, 256, 0, stream>>>(enc_w, wpe);
  perm2_k<<<768, 256, 0, stream>>>(dec_w, wpe + (size_t)3 * 256 * 3072);
  cvt_k<<<1536, 256, 0, stream>>>(skip_w, skip_wb, 3 * 256 * 512);
  hipMemsetAsync(cls1_wb, 0, 256 * 256 * 2, stream);
  cvt_k<<<128, 256, 0, stream>>>(cls1_w, cls1_wb, 128 * 256);
  hipMemsetAsync(wp6, 0, 256 * 128 * 2, stream);
  cvt_k<<<32, 256, 0, stream>>>(cls2_w, wp6, 64 * 128);

  // ---- encoder block 0 ----
  hipMemsetAsync(stats, 0, 4096, stream);
  enc0_k<<<1024, 256, 0, stream>>>(verts, spirals, enc0_w, ct);
  stats2_k<<<512, 256, 0, stream>>>(ct, stats);
  bnrelu2_k<<<512, 256, 0, stream>>>(ct, stats, enc0_g, enc0_be, nullptr, nullptr, out0, sesum, 256);
  se_k<<<2, 256, 0, stream>>>(sesum, se_w1, se_w2, sig);

  // ---- encoder blocks 1..3 (x_{i-1} = out_{i-1} * sig_{i-1}, fused into staging/resid) ----
  for (int i = 1; i < 4; ++i) {
    hipMemsetAsync(stats, 0, 4096, stream);
    gemm2_k<256><<<512, 512, 0, stream>>>(outs[i - 1], nullptr, 256,
                                          spirals + (size_t)i * V_N * 12, 12,
                                          wpe + (size_t)(i - 1) * 256 * 3072, 3072,
                                          sig + (i - 1) * 512, nullptr,
                                          ct, nullptr, 256, stats);
    bnrelu2_k<<<512, 256, 0, stream>>>(ct, stats, enc_g + (i - 1) * 256, enc_be + (i - 1) * 256,
                                       outs[i - 1], sig + (i - 1) * 512, outs[i], sesum, 256);
    se_k<<<2, 256, 0, stream>>>(sesum, se_w1 + (size_t)i * 32 * 256,
                                se_w2 + (size_t)i * 256 * 32, sig + i * 512);
  }

  // decoder input x = out3 * sig3 (materialized once; out3 aliases ct)
  scale_k<<<8192, 256, 0, stream>>>(ct, sig + 3 * 512, xd);

  // ---- decoder blocks ----
  for (int i = 0; i < 3; ++i) {
    gemm2_k<256><<<512, 512, 0, stream>>>(xd, outs[2 - i], 256, nullptr, 2,
                                          skip_wb + (size_t)i * 256 * 512, 512,
                                          nullptr, sig + (2 - i) * 512,
                                          tb, skip_b + i * 256, 256, nullptr);       // x1 -> tb
    hipMemsetAsync(stats, 0, 4096, stream);
    gemm2_k<256><<<512, 512, 0, stream>>>(tb, nullptr, 256,
                                          spirals + (size_t)(2 - i) * V_N * 12, 12,
                                          wpe + (size_t)(3 + i) * 256 * 3072, 3072,
                                          nullptr, nullptr,
                                          outs[2 - i], nullptr, 256, stats);          // conv -> out[2-i]
    bnrelu2_k<<<512, 256, 0, stream>>>(outs[2 - i], stats, dec_g + i * 256, dec_be + i * 256,
                                       tb, nullptr, xd, nullptr, 256);                // x -> xd
  }

  // ---- classifier ----
  hipMemsetAsync(stats, 0, 4096, stream);
  gemm2_k<256><<<512, 512, 0, stream>>>(xd, nullptr, 256, nullptr, 1,
                                        cls1_wb, 256, nullptr, nullptr, ct, nullptr, 128, stats);
  bnrelu2_k<<<256, 256, 0, stream>>>(ct, stats, cls1_g, cls1_be, nullptr, nullptr, ct, nullptr, 128);
  hipMemsetAsync(stats, 0, 4096, stream);
  gemm2_k<128><<<512, 512, 0, stream>>>(ct, nullptr, 128, nullptr, 1,
                                        wp6, 128, nullptr, nullptr, tb, nullptr, 64, stats);
  bnrelu2_k<<<128, 256, 0, stream>>>(tb, stats, cls2_g, cls2_be, nullptr, nullptr, tb, nullptr, 64);
  cls3_k<<<128, 256, 0, stream>>>(tb, cls3_w, cls3_b, (float*)d_out);
}

// Round 10
// 1415.263 us; speedup vs baseline: 1.8488x; 1.3418x over previous
//
#include <hip/hip_runtime.h>

typedef unsigned short u16;
using f16x8 = __attribute__((ext_vector_type(8))) _Float16;  // 8 fp16 (4 VGPRs)
using f32x4 = __attribute__((ext_vector_type(4))) float;

#define V_N 16384
#define M_N 32768

__device__ __forceinline__ float h2f(u16 u) {
  _Float16 h; __builtin_memcpy(&h, &u, 2); return (float)h;
}
__device__ __forceinline__ u16 f2h(float f) {
  _Float16 h = (_Float16)f; u16 u; __builtin_memcpy(&u, &h, 2); return u;
}

// ---------- prep kernels ----------
// LDS-transpose weight permute: wp[o][t*256+c] = f2h(w[o][c*12+t])
__global__ __launch_bounds__(256) void perm2_k(const float* __restrict__ w, u16* __restrict__ wp) {
  __shared__ u16 l[3072];
  int o = blockIdx.x & 255, layer = blockIdx.x >> 8;
  int t = threadIdx.x;
  const float* src = w + ((size_t)layer * 256 + o) * 3072;
  u16* dst = wp + ((size_t)layer * 256 + o) * 3072;
  float2 v[6];
  #pragma unroll
  for (int q = 0; q < 6; ++q) v[q] = *(const float2*)(src + t * 12 + q * 2);
  const float* vf = (const float*)v;
  #pragma unroll
  for (int m = 0; m < 12; ++m) l[m * 256 + t] = f2h(vf[m]);   // c = t
  __syncthreads();
  unsigned* d32 = (unsigned*)dst;
  const unsigned* l32 = (const unsigned*)l;
  #pragma unroll
  for (int q = 0; q < 6; ++q) d32[t * 6 + q] = l32[t * 6 + q];
}

// flat f32 -> fp16 convert
__global__ __launch_bounds__(256) void cvt_k(const float* __restrict__ w, u16* __restrict__ wb, int n) {
  int i = blockIdx.x * 256 + threadIdx.x;
  if (i < n) wb[i] = f2h(w[i]);
}

// per-batch SE-scale fold into weights: o[b][i] = w[i] * sig[b][channel]
// sel=255: enc conv (all K scaled, c = i&255). sel=511: skip (only k>=256 scaled, c=k&255).
__global__ __launch_bounds__(256) void wscale_k(const u16* __restrict__ w, const float* __restrict__ sig,
                                                u16* __restrict__ o, int n, int sel) {
  int i = blockIdx.x * 256 + threadIdx.x;
  if (i >= n) return;
  float wv = h2f(w[i]);
  int k = i & sel;
  int c = k & 255;
  #pragma unroll
  for (int b = 0; b < 2; ++b) {
    float s = (sel == 511 && k < 256) ? 1.f : sig[b * 256 + c];
    o[(long)b * n + i] = f2h(wv * s);
  }
}

// ---------- encoder block 0 conv (C_in=3, K=36), f32 in -> fp16 out ----------
__global__ __launch_bounds__(256) void enc0_k(const float* __restrict__ verts, const int* __restrict__ sp,
                                              const float* __restrict__ w0, u16* __restrict__ y) {
  __shared__ float xs[32][36];
  int t = threadIdx.x;
  int r0 = blockIdx.x * 32;
  for (int s = t; s < 32 * 12; s += 256) {
    int row = s / 12, tt = s - row * 12;
    int gr = r0 + row;
    int b = gr >> 14, v = gr & (V_N - 1);
    int j = sp[tt * V_N + v];
    const float* p = verts + ((long)b * V_N + j) * 3;
    xs[row][tt]      = p[0];
    xs[row][12 + tt] = p[1];
    xs[row][24 + tt] = p[2];
  }
  __syncthreads();
  float w[36];
  #pragma unroll
  for (int k = 0; k < 36; ++k) w[k] = w0[t * 36 + k];
  for (int row = 0; row < 32; ++row) {
    float a = 0.f;
    #pragma unroll
    for (int k = 0; k < 36; ++k) a += w[k] * xs[row][k];
    y[(long)(r0 + row) * 256 + t] = f2h(a);
  }
}

// ---------- staged MFMA GEMM: 128M x 256N tile, 512 thr, 2-tap-deep gather pipeline ----------
// Y[M x Ostore](fp16) = gatherA[M x (L*CT)] * Wt_b^T (+f32 bias) (+fused BN stats).
// Gather: row = b*V + sp[l*V+v]; dense: row = bm+srow, P0 (l==0) / P1 (l>=1).
// Wt_b = Wt + batch*wstride (per-batch SE-folded weights; wstride=0 -> shared). ldw = L*CT.
template<int CT>
__global__ __launch_bounds__(512) void gemm2_k(
    const u16* __restrict__ P0, const u16* __restrict__ P1, int lda,
    const int* __restrict__ sp, int L,
    const u16* __restrict__ Wt, long wstride,
    u16* __restrict__ Yb, const float* __restrict__ bias, int Ostore,
    float* __restrict__ stats)
{
  constexpr int KC  = CT >> 5;     // K-chunks of 32 per tap
  constexpr int SPT = CT >> 5;     // 16B segs staged per thread (128 rows, 4 slots/row)
  __shared__ __align__(16) u16 lA[128 * CT];
  const int tid  = threadIdx.x;
  const int wave = tid >> 6, lane = tid & 63;
  const int wm = (wave & 1) * 64, wn = (wave >> 1) * 64;
  const int lr = lane & 15, lq = lane >> 4;
  const int bm = blockIdx.x * 128;
  const int batch = bm >> 14;
  const int srow = tid >> 2, slot = tid & 3;
  const bool gat = (sp != nullptr);
  const int ldw = L * CT;
  const int TK = L * KC;
  const u16* Wb = Wt + (long)batch * wstride;

  // B fragment pointers
  const u16* bp[4];
  #pragma unroll
  for (int nt = 0; nt < 4; ++nt) bp[nt] = Wb + (long)(wn + nt * 16 + lr) * ldw + lq * 8;

  // ---- prologue: 2-deep staging (taps 0 and 1 both in flight), idx 2 taps ahead ----
  const long rowbase = gat ? ((long)batch * V_N * lda) : 0;
  const int vloc = (bm & (V_N - 1)) + srow;
  const u16* Pd1 = P1 ? P1 : P0;

  f16x8 rA[SPT], rB[SPT];
  {
    const u16* b0 = gat ? (P0 + rowbase + (long)sp[vloc] * lda)
                        : (P0 + (long)(bm + srow) * lda);
    #pragma unroll
    for (int j = 0; j < SPT; ++j) rA[j] = *(const f16x8*)(b0 + (slot * SPT + j) * 8);
  }
  if (L > 1) {
    const u16* b1 = gat ? (P0 + rowbase + (long)sp[V_N + vloc] * lda)
                        : (Pd1 + (long)(bm + srow) * lda);
    #pragma unroll
    for (int j = 0; j < SPT; ++j) rB[j] = *(const f16x8*)(b1 + (slot * SPT + j) * 8);
  }
  int idxE = (gat && L > 2) ? sp[2 * V_N + vloc] : 0;
  int idxO = (gat && L > 3) ? sp[3 * V_N + vloc] : 0;

  f16x8 bv0[4], bv1[4];
  #pragma unroll
  for (int nt = 0; nt < 4; ++nt) bv0[nt] = *(const f16x8*)(bp[nt]);
  #pragma unroll
  for (int nt = 0; nt < 4; ++nt) bv1[nt] = *(const f16x8*)(bp[nt] + 32);

  f32x4 acc[4][4];
  #pragma unroll
  for (int i = 0; i < 4; ++i)
    #pragma unroll
    for (int j = 0; j < 4; ++j) acc[i][j] = (f32x4){0.f, 0.f, 0.f, 0.f};

  auto stage = [&](const f16x8* r) {
    __syncthreads();
    #pragma unroll
    for (int j = 0; j < SPT; ++j) {
      int ss = ((slot * SPT + j) ^ (srow & 7)) * 8;
      *(f16x8*)(&lA[srow * CT + ss]) = r[j];
    }
    __syncthreads();
  };

  auto mfma_phase = [&](int l) {
    f16x8 a0[4], a1[4];
    #pragma unroll
    for (int mt = 0; mt < 4; ++mt) {
      int row = wm + mt * 16 + lr;
      a0[mt] = *(const f16x8*)(&lA[row * CT + ((lq ^ (row & 7)) * 8)]);
    }
    #pragma unroll
    for (int kc = 0; kc < KC; kc += 2) {
      const int gs = l * KC + kc;
      #pragma unroll
      for (int mt = 0; mt < 4; ++mt) {
        int row = wm + mt * 16 + lr;
        a1[mt] = *(const f16x8*)(&lA[row * CT + ((((kc + 1) * 4 + lq) ^ (row & 7)) * 8)]);
      }
      f16x8 t0[4];
      if (gs + 2 < TK) {
        #pragma unroll
        for (int nt = 0; nt < 4; ++nt) t0[nt] = *(const f16x8*)(bp[nt] + (long)(gs + 2) * 32);
      }
      #pragma unroll
      for (int mt = 0; mt < 4; ++mt)
        #pragma unroll
        for (int nt = 0; nt < 4; ++nt)
          acc[mt][nt] = __builtin_amdgcn_mfma_f32_16x16x32_f16(a0[mt], bv0[nt], acc[mt][nt], 0, 0, 0);
      if (kc + 2 < KC) {
        #pragma unroll
        for (int mt = 0; mt < 4; ++mt) {
          int row = wm + mt * 16 + lr;
          a0[mt] = *(const f16x8*)(&lA[row * CT + ((((kc + 2) * 4 + lq) ^ (row & 7)) * 8)]);
        }
      }
      f16x8 t1[4];
      if (gs + 3 < TK) {
        #pragma unroll
        for (int nt = 0; nt < 4; ++nt) t1[nt] = *(const f16x8*)(bp[nt] + (long)(gs + 3) * 32);
      }
      #pragma unroll
      for (int mt = 0; mt < 4; ++mt)
        #pragma unroll
        for (int nt = 0; nt < 4; ++nt)
          acc[mt][nt] = __builtin_amdgcn_mfma_f32_16x16x32_f16(a1[mt], bv1[nt], acc[mt][nt], 0, 0, 0);
      #pragma unroll
      for (int nt = 0; nt < 4; ++nt) { bv0[nt] = t0[nt]; bv1[nt] = t1[nt]; }
    }
  };

  for (int l = 0; l < L; l += 2) {
    // EVEN tap: consume rA (its loads got 2 full phases); refill rA for tap l+2
    stage(rA);
    if (l + 2 < L) {
      const u16* nb = gat ? (P0 + rowbase + (long)idxE * lda)
                          : (Pd1 + (long)(bm + srow) * lda);
      #pragma unroll
      for (int j = 0; j < SPT; ++j) rA[j] = *(const f16x8*)(nb + (slot * SPT + j) * 8);
      if (gat && l + 4 < L) idxE = sp[(long)(l + 4) * V_N + vloc];
    }
    mfma_phase(l);
    if (l + 1 < L) {
      // ODD tap: consume rB; refill rB for tap l+3
      stage(rB);
      if (l + 3 < L) {
        const u16* nb = gat ? (P0 + rowbase + (long)idxO * lda)
                            : (Pd1 + (long)(bm + srow) * lda);
        #pragma unroll
        for (int j = 0; j < SPT; ++j) rB[j] = *(const f16x8*)(nb + (slot * SPT + j) * 8);
        if (gat && l + 5 < L) idxO = sp[(long)(l + 5) * V_N + vloc];
      }
      mfma_phase(l + 1);
    }
  }

  // epilogue: C/D layout col=lane&15, row=(lane>>4)*4+reg [guide m89]; fused stats
  #pragma unroll
  for (int nt = 0; nt < 4; ++nt) {
    int col = wn + nt * 16 + lr;
    if (col < Ostore) {
      float bv = bias ? bias[col] : 0.f;
      float s1 = 0.f, s2 = 0.f;
      #pragma unroll
      for (int mt = 0; mt < 4; ++mt) {
        #pragma unroll
        for (int rg = 0; rg < 4; ++rg) {
          int row = bm + wm + mt * 16 + lq * 4 + rg;
          float v = acc[mt][nt][rg] + bv;
          Yb[(long)row * Ostore + col] = f2h(v);
          s1 += v; s2 += v * v;
        }
      }
      if (stats) {
        s1 += __shfl_xor(s1, 16); s1 += __shfl_xor(s1, 32);
        s2 += __shfl_xor(s2, 16); s2 += __shfl_xor(s2, 32);
        if (lq == 0) {
          atomicAdd(&stats[col], s1);
          atomicAdd(&stats[Ostore + col], s2);
        }
      }
    }
  }
}

// ---------- stats for enc0 output (O=256), vectorized ----------
__global__ __launch_bounds__(256) void stats2_k(const u16* __restrict__ y, float* __restrict__ st) {
  __shared__ float s1L[256], s2L[256];
  int tid = threadIdx.x;
  int ci = (tid & 63) * 4;
  int r0 = blockIdx.x * 64 + (tid >> 6);
  float a1[4] = {0,0,0,0}, a2[4] = {0,0,0,0};
  for (int it = 0; it < 16; ++it) {
    long i = ((long)r0 + it * 4) * 256 + ci;
    uint2 pv = *(const uint2*)(y + i);
    float v0 = h2f((u16)(pv.x & 0xffff)), v1 = h2f((u16)(pv.x >> 16));
    float v2 = h2f((u16)(pv.y & 0xffff)), v3 = h2f((u16)(pv.y >> 16));
    a1[0] += v0; a1[1] += v1; a1[2] += v2; a1[3] += v3;
    a2[0] += v0*v0; a2[1] += v1*v1; a2[2] += v2*v2; a2[3] += v3*v3;
  }
  s1L[tid] = 0.f; s2L[tid] = 0.f;
  __syncthreads();
  #pragma unroll
  for (int j = 0; j < 4; ++j) { atomicAdd(&s1L[ci + j], a1[j]); atomicAdd(&s2L[ci + j], a2[j]); }
  __syncthreads();
  atomicAdd(&st[tid], s1L[tid]);
  atomicAdd(&st[256 + tid], s2L[tid]);
}

// ---------- vectorized BN+ReLU (+fp16 residual, optional per-channel resid scale) (+SE sums) ----------
__global__ __launch_bounds__(256) void bnrelu2_k(
    const u16* __restrict__ y, const float* __restrict__ st,
    const float* __restrict__ g, const float* __restrict__ be,
    const u16* __restrict__ resid, const float* __restrict__ rscale,
    u16* __restrict__ ob, float* __restrict__ ses, int O)
{
  __shared__ float sL[256];
  int tid = threadIdx.x;
  int tpr = O >> 2;
  int rpi = 256 / tpr;
  int ci = (tid & (tpr - 1)) * 4;
  int row0 = blockIdx.x * (rpi * 16);
  int r0 = row0 + (tid / tpr);
  int b = row0 >> 14;
  float mean[4], sc[4], sh[4], rs[4];
  #pragma unroll
  for (int j = 0; j < 4; ++j) {
    int c = ci + j;
    float m = st[c] * (1.f / 32768.f);
    float var = st[O + c] * (1.f / 32768.f) - m * m;
    mean[j] = m;
    sc[j] = rsqrtf(fmaxf(var, 0.f) + 1e-5f) * g[c];
    sh[j] = be[c];
    rs[j] = rscale ? rscale[b * 256 + c] : 1.f;
  }
  float ss[4] = {0,0,0,0};
  for (int it = 0; it < 16; ++it) {
    long i = ((long)r0 + (long)it * rpi) * O + ci;
    uint2 pv = *(const uint2*)(y + i);
    float v[4];
    v[0] = fmaxf((h2f((u16)(pv.x & 0xffff)) - mean[0]) * sc[0] + sh[0], 0.f);
    v[1] = fmaxf((h2f((u16)(pv.x >> 16))    - mean[1]) * sc[1] + sh[1], 0.f);
    v[2] = fmaxf((h2f((u16)(pv.y & 0xffff)) - mean[2]) * sc[2] + sh[2], 0.f);
    v[3] = fmaxf((h2f((u16)(pv.y >> 16))    - mean[3]) * sc[3] + sh[3], 0.f);
    if (resid) {
      uint2 rv = *(const uint2*)(resid + i);
      v[0] += h2f((u16)(rv.x & 0xffff)) * rs[0]; v[1] += h2f((u16)(rv.x >> 16)) * rs[1];
      v[2] += h2f((u16)(rv.y & 0xffff)) * rs[2]; v[3] += h2f((u16)(rv.y >> 16)) * rs[3];
    }
    uint2 pk;
    pk.x = (unsigned)f2h(v[0]) | ((unsigned)f2h(v[1]) << 16);
    pk.y = (unsigned)f2h(v[2]) | ((unsigned)f2h(v[3]) << 16);
    *(uint2*)(ob + i) = pk;
    #pragma unroll
    for (int j = 0; j < 4; ++j) ss[j] += v[j];
  }
  if (ses) {
    sL[tid] = 0.f;
    __syncthreads();
    #pragma unroll
    for (int j = 0; j < 4; ++j) atomicAdd(&sL[ci + j], ss[j]);
    __syncthreads();
    atomicAdd(&ses[b * O + tid], sL[tid]);
  }
}

// ---------- SE gate ----------
__global__ void se_k(const float* __restrict__ ses, const float* __restrict__ w1,
                     const float* __restrict__ w2, float* __restrict__ sig)
{
  __shared__ float s[256];
  __shared__ float h[32];
  int b = blockIdx.x, t = threadIdx.x;
  s[t] = ses[b * 256 + t] * (1.f / 16384.f);
  __syncthreads();
  if (t < 32) {
    float a = 0.f;
    for (int c = 0; c < 256; ++c) a += w1[t * 256 + c] * s[c];
    h[t] = fmaxf(a, 0.f);
  }
  __syncthreads();
  float a = 0.f;
  #pragma unroll
  for (int r = 0; r < 32; ++r) a += w2[t * 32 + r] * h[r];
  sig[b * 256 + t] = 1.f / (1.f + expf(-a));
}

// ---------- x = out * sig (single use: decoder input materialization) ----------
__global__ __launch_bounds__(256) void scale_k(const u16* __restrict__ t, const float* __restrict__ sig,
                                               u16* __restrict__ xb)
{
  long i = ((long)blockIdx.x * 256 + threadIdx.x) * 4;
  int b = (int)(i >> 22);
  int c = (int)(i & 255);
  uint2 pv = *(const uint2*)(t + i);
  const float* sgp = sig + b * 256 + c;
  float v0 = h2f((u16)(pv.x & 0xffff)) * sgp[0];
  float v1 = h2f((u16)(pv.x >> 16))    * sgp[1];
  float v2 = h2f((u16)(pv.y & 0xffff)) * sgp[2];
  float v3 = h2f((u16)(pv.y >> 16))    * sgp[3];
  uint2 pk;
  pk.x = (unsigned)f2h(v0) | ((unsigned)f2h(v1) << 16);
  pk.y = (unsigned)f2h(v2) | ((unsigned)f2h(v3) << 16);
  *(uint2*)(xb + i) = pk;
}

// ---------- final head ----------
__global__ __launch_bounds__(256) void cls3_k(const u16* __restrict__ h2, const float* __restrict__ w,
                                              const float* __restrict__ b, float* __restrict__ out)
{
  __shared__ float ws[64];
  int t = threadIdx.x;
  if (t < 64) ws[t] = w[t];
  __syncthreads();
  int r = blockIdx.x * 256 + t;
  const u16* p = h2 + (long)r * 64;
  float a = b[0];
  #pragma unroll
  for (int c = 0; c < 64; ++c) a += ws[c] * h2f(p[c]);
  out[r] = a;
}

extern "C" void kernel_launch(void* const* d_in, const int* in_sizes, int n_in,
                              void* d_out, int out_size, void* d_ws, size_t ws_size,
                              hipStream_t stream)
{
  (void)in_sizes; (void)n_in; (void)out_size; (void)ws_size;
  const float* verts   = (const float*)d_in[0];
  const int*   spirals = (const int*)d_in[1];
  const float* enc0_w  = (const float*)d_in[2];
  const float* enc0_g  = (const float*)d_in[4];
  const float* enc0_be = (const float*)d_in[5];
  const float* enc_w   = (const float*)d_in[6];
  const float* enc_g   = (const float*)d_in[8];
  const float* enc_be  = (const float*)d_in[9];
  const float* se_w1   = (const float*)d_in[10];
  const float* se_w2   = (const float*)d_in[11];
  const float* skip_w  = (const float*)d_in[12];
  const float* skip_b  = (const float*)d_in[13];
  const float* dec_w   = (const float*)d_in[14];
  const float* dec_g   = (const float*)d_in[16];
  const float* dec_be  = (const float*)d_in[17];
  const float* cls1_w  = (const float*)d_in[18];
  const float* cls1_g  = (const float*)d_in[20];
  const float* cls1_be = (const float*)d_in[21];
  const float* cls2_w  = (const float*)d_in[22];
  const float* cls2_g  = (const float*)d_in[24];
  const float* cls2_be = (const float*)d_in[25];
  const float* cls3_w  = (const float*)d_in[26];
  const float* cls3_b  = (const float*)d_in[27];

  // --- workspace (~118 MB) ---
  char* p = (char*)d_ws;
  auto alloc = [&](size_t n) { char* q = p; p += (n + 255) & ~(size_t)255; return q; };
  u16* wpe     = (u16*)alloc((size_t)6 * 256 * 3072 * 2);       // 6 permuted conv weights
  u16* wpe_s   = (u16*)alloc((size_t)3 * 2 * 256 * 3072 * 2);   // enc, per-batch SE-folded
  u16* skip_wb = (u16*)alloc((size_t)3 * 256 * 512 * 2);
  u16* skip_s  = (u16*)alloc((size_t)3 * 2 * 256 * 512 * 2);    // skip, per-batch folded
  u16* cls1_wb = (u16*)alloc((size_t)256 * 256 * 2);            // zero-padded to 256 rows
  u16* wp6     = (u16*)alloc((size_t)256 * 128 * 2);            // zero-padded to 256 rows
  float* stats = (float*)alloc(2048);
  float* sesum = (float*)alloc(2048);                           // contiguous after stats
  float* sig   = (float*)alloc(4 * 2048);                       // sig_i = sig + i*512
  u16* out0 = (u16*)alloc((size_t)M_N * 256 * 2);
  u16* out1 = (u16*)alloc((size_t)M_N * 256 * 2);
  u16* out2 = (u16*)alloc((size_t)M_N * 256 * 2);
  u16* ct   = (u16*)alloc((size_t)M_N * 256 * 2);               // conv temp; aliases out3
  u16* tb   = (u16*)alloc((size_t)M_N * 256 * 2);
  u16* xd   = (u16*)alloc((size_t)M_N * 256 * 2);
  u16* outs[4] = {out0, out1, out2, ct};
  const size_t WENC = (size_t)256 * 3072;      // elems per enc weight copy
  const size_t WSKP = (size_t)256 * 512;

  // prep
  perm2_k<<<768, 256, 0, stream>>>(enc_w, wpe);
  perm2_k<<<768, 256, 0, stream>>>(dec_w, wpe + (size_t)3 * WENC);
  cvt_k<<<1536, 256, 0, stream>>>(skip_w, skip_wb, 3 * 256 * 512);
  hipMemsetAsync(cls1_wb, 0, 256 * 256 * 2, stream);
  cvt_k<<<128, 256, 0, stream>>>(cls1_w, cls1_wb, 128 * 256);
  hipMemsetAsync(wp6, 0, 256 * 128 * 2, stream);
  cvt_k<<<32, 256, 0, stream>>>(cls2_w, wp6, 64 * 128);

  // ---- encoder block 0 ----
  hipMemsetAsync(stats, 0, 4096, stream);
  enc0_k<<<1024, 256, 0, stream>>>(verts, spirals, enc0_w, ct);
  stats2_k<<<512, 256, 0, stream>>>(ct, stats);
  bnrelu2_k<<<512, 256, 0, stream>>>(ct, stats, enc0_g, enc0_be, nullptr, nullptr, out0, sesum, 256);
  se_k<<<2, 256, 0, stream>>>(sesum, se_w1, se_w2, sig);

  // ---- encoder blocks 1..3 (SE scale folded into per-batch weights) ----
  for (int i = 1; i < 4; ++i) {
    wscale_k<<<3072, 256, 0, stream>>>(wpe + (size_t)(i - 1) * WENC, sig + (i - 1) * 512,
                                       wpe_s + (size_t)(i - 1) * 2 * WENC, (int)WENC, 255);
    hipMemsetAsync(stats, 0, 4096, stream);
    gemm2_k<256><<<256, 512, 0, stream>>>(outs[i - 1], nullptr, 256,
                                          spirals + (size_t)i * V_N * 12, 12,
                                          wpe_s + (size_t)(i - 1) * 2 * WENC, (long)WENC,
                                          ct, nullptr, 256, stats);
    bnrelu2_k<<<512, 256, 0, stream>>>(ct, stats, enc_g + (i - 1) * 256, enc_be + (i - 1) * 256,
                                       outs[i - 1], sig + (i - 1) * 512, outs[i], sesum, 256);
    se_k<<<2, 256, 0, stream>>>(sesum, se_w1 + (size_t)i * 32 * 256,
                                se_w2 + (size_t)i * 256 * 32, sig + i * 512);
  }

  // decoder input x = out3 * sig3 (materialized once; out3 aliases ct)
  scale_k<<<8192, 256, 0, stream>>>(ct, sig + 3 * 512, xd);

  // ---- decoder blocks ----
  for (int i = 0; i < 3; ++i) {
    wscale_k<<<512, 256, 0, stream>>>(skip_wb + (size_t)i * WSKP, sig + (2 - i) * 512,
                                      skip_s + (size_t)i * 2 * WSKP, (int)WSKP, 511);
    gemm2_k<256><<<256, 512, 0, stream>>>(xd, outs[2 - i], 256, nullptr, 2,
                                          skip_s + (size_t)i * 2 * WSKP, (long)WSKP,
                                          tb, skip_b + i * 256, 256, nullptr);       // x1 -> tb
    hipMemsetAsync(stats, 0, 4096, stream);
    gemm2_k<256><<<256, 512, 0, stream>>>(tb, nullptr, 256,
                                          spirals + (size_t)(2 - i) * V_N * 12, 12,
                                          wpe + (size_t)(3 + i) * WENC, 0,
                                          outs[2 - i], nullptr, 256, stats);          // conv -> out[2-i]
    bnrelu2_k<<<512, 256, 0, stream>>>(outs[2 - i], stats, dec_g + i * 256, dec_be + i * 256,
                                       tb, nullptr, xd, nullptr, 256);                // x -> xd
  }

  // ---- classifier ----
  hipMemsetAsync(stats, 0, 4096, stream);
  gemm2_k<256><<<256, 512, 0, stream>>>(xd, nullptr, 256, nullptr, 1,
                                        cls1_wb, 0, ct, nullptr, 128, stats);
  bnrelu2_k<<<256, 256, 0, stream>>>(ct, stats, cls1_g, cls1_be, nullptr, nullptr, ct, nullptr, 128);
  hipMemsetAsync(stats, 0, 4096, stream);
  gemm2_k<128><<<256, 512, 0, stream>>>(ct, nullptr, 128, nullptr, 1,
                                        wp6, 0, tb, nullptr, 64, stats);
  bnrelu2_k<<<128, 256, 0, stream>>>(tb, stats, cls2_g, cls2_be, nullptr, nullptr, tb, nullptr, 64);
  cls3_k<<<128, 256, 0, stream>>>(tb, cls3_w, cls3_b, (float*)d_out);
}

// Round 11
// 1197.574 us; speedup vs baseline: 2.1849x; 1.1818x over previous
//
#include <hip/hip_runtime.h>

typedef unsigned short u16;
using f16x8 = __attribute__((ext_vector_type(8))) _Float16;  // 8 fp16 (4 VGPRs)
using f32x4 = __attribute__((ext_vector_type(4))) float;

#define V_N 16384
#define M_N 32768

__device__ __forceinline__ float h2f(u16 u) {
  _Float16 h; __builtin_memcpy(&h, &u, 2); return (float)h;
}
__device__ __forceinline__ u16 f2h(float f) {
  _Float16 h = (_Float16)f; u16 u; __builtin_memcpy(&u, &h, 2); return u;
}

// async global->LDS DMA, 16B per lane; LDS dest = wave-uniform base + lane*16
__device__ __forceinline__ void dma16(const u16* g, u16* l) {
  __builtin_amdgcn_global_load_lds(
      (const __attribute__((address_space(1))) void*)(const void*)g,
      (__attribute__((address_space(3))) void*)(void*)l, 16, 0, 0);
}

// ---------- prep kernels ----------
// LDS-transpose weight permute: wp[o][t*256+c] = f2h(w[o][c*12+t])
__global__ __launch_bounds__(256) void perm2_k(const float* __restrict__ w, u16* __restrict__ wp) {
  __shared__ u16 l[3072];
  int o = blockIdx.x & 255, layer = blockIdx.x >> 8;
  int t = threadIdx.x;
  const float* src = w + ((size_t)layer * 256 + o) * 3072;
  u16* dst = wp + ((size_t)layer * 256 + o) * 3072;
  float2 v[6];
  #pragma unroll
  for (int q = 0; q < 6; ++q) v[q] = *(const float2*)(src + t * 12 + q * 2);
  const float* vf = (const float*)v;
  #pragma unroll
  for (int m = 0; m < 12; ++m) l[m * 256 + t] = f2h(vf[m]);   // c = t
  __syncthreads();
  unsigned* d32 = (unsigned*)dst;
  const unsigned* l32 = (const unsigned*)l;
  #pragma unroll
  for (int q = 0; q < 6; ++q) d32[t * 6 + q] = l32[t * 6 + q];
}

// flat f32 -> fp16 convert
__global__ __launch_bounds__(256) void cvt_k(const float* __restrict__ w, u16* __restrict__ wb, int n) {
  int i = blockIdx.x * 256 + threadIdx.x;
  if (i < n) wb[i] = f2h(w[i]);
}

// per-batch SE-scale fold into weights: o[b][i] = w[i] * sig[b][channel]
// sel=255: enc conv (all K scaled). sel=511: skip (only k>=256 scaled).
__global__ __launch_bounds__(256) void wscale_k(const u16* __restrict__ w, const float* __restrict__ sig,
                                                u16* __restrict__ o, int n, int sel) {
  int i = blockIdx.x * 256 + threadIdx.x;
  if (i >= n) return;
  float wv = h2f(w[i]);
  int k = i & sel;
  int c = k & 255;
  #pragma unroll
  for (int b = 0; b < 2; ++b) {
    float s = (sel == 511 && k < 256) ? 1.f : sig[b * 256 + c];
    o[(long)b * n + i] = f2h(wv * s);
  }
}

// ---------- encoder block 0 conv (C_in=3, K=36), f32 in -> fp16 out ----------
__global__ __launch_bounds__(256) void enc0_k(const float* __restrict__ verts, const int* __restrict__ sp,
                                              const float* __restrict__ w0, u16* __restrict__ y) {
  __shared__ float xs[32][36];
  int t = threadIdx.x;
  int r0 = blockIdx.x * 32;
  for (int s = t; s < 32 * 12; s += 256) {
    int row = s / 12, tt = s - row * 12;
    int gr = r0 + row;
    int b = gr >> 14, v = gr & (V_N - 1);
    int j = sp[tt * V_N + v];
    const float* p = verts + ((long)b * V_N + j) * 3;
    xs[row][tt]      = p[0];
    xs[row][12 + tt] = p[1];
    xs[row][24 + tt] = p[2];
  }
  __syncthreads();
  float w[36];
  #pragma unroll
  for (int k = 0; k < 36; ++k) w[k] = w0[t * 36 + k];
  for (int row = 0; row < 32; ++row) {
    float a = 0.f;
    #pragma unroll
    for (int k = 0; k < 36; ++k) a += w[k] * xs[row][k];
    y[(long)(r0 + row) * 256 + t] = f2h(a);
  }
}

// ---------- DMA-staged MFMA GEMM: 128M x 256N tile, 512 thr, half-tap double buffer ----------
// Y[M x Ostore](fp16) = gatherA[M x (L*CT)] * Wt_b^T (+f32 bias) (+fused BN stats).
// Each tap split into 2 half-stages of CT bytes/row; LDS buf0(h=0)/buf1(h=1), 32KB each (CT=256).
// Per stage: sync -> issue DMA for NEXT stage -> compute current from the other buffer.
template<int CT>
__global__ __launch_bounds__(512) void gemm3_k(
    const u16* __restrict__ P0, const u16* __restrict__ P1, int lda,
    const int* __restrict__ sp, int L,
    const u16* __restrict__ Wt, long wstride,
    u16* __restrict__ Yb, const float* __restrict__ bias, int Ostore,
    float* __restrict__ stats)
{
  constexpr int KC   = CT >> 5;          // k-chunks (32 elems) per tap
  constexpr int KCH  = KC >> 1;          // k-chunks per half-stage
  constexpr int HROW = CT >> 1;          // elems per half-row (= CT bytes)
  constexpr int CHT  = CT >> 4;          // 16B chunks per half-row
  constexpr int RSH  = (CHT == 16) ? 4 : 3;
  constexpr int CMSK = CHT - 1;
  constexpr int RPI  = 64 / CHT;         // rows per DMA instruction
  constexpr int QN   = 16 / RPI;         // DMA instrs per wave per stage
  __shared__ __align__(16) u16 lA0[64 * CT];    // 128 rows x CT bytes (h=0)
  __shared__ __align__(16) u16 lA1[64 * CT];    // (h=1)
  const int tid  = threadIdx.x;
  const int wave = tid >> 6, lane = tid & 63;
  const int wm = (wave & 1) * 64, wn = (wave >> 1) * 64;
  const int lr = lane & 15, lq = lane >> 4;
  const int bm = blockIdx.x * 128;
  const int batch = bm >> 14;
  const int vbase = bm & (V_N - 1);
  const int qrow = lane >> RSH;          // row within DMA instr
  const int qchunk = lane & CMSK;        // 16B chunk within row
  const bool gat = (sp != nullptr);
  const int TK = L * KC;
  const long rowb = (long)batch * V_N;   // gather row base (rows)
  const u16* Pd1 = P1 ? P1 : P0;
  const u16* Wb = Wt + (long)batch * wstride;
  const int ldw = L * CT;

  // B fragment pointers
  const u16* bp[4];
  #pragma unroll
  for (int nt = 0; nt < 4; ++nt) bp[nt] = Wb + (long)(wn + nt * 16 + lr) * ldw + lq * 8;

  auto load_idx = [&](int tap) -> int {
    int v = 0;
    if (lane < 16) v = sp[(long)tap * V_N + vbase + wave * 16 + lane];
    return v;
  };

  auto dma_half = [&](u16* buf, const u16* src, int idxreg, int h) {
    u16* wbase = buf + wave * (16 * HROW);
    #pragma unroll
    for (int q = 0; q < QN; ++q) {
      int rloc = wave * 16 + q * RPI + qrow;
      long grow;
      if (gat) grow = rowb + (long)__shfl(idxreg, q * RPI + qrow, 64);
      else     grow = bm + rloc;
      const u16* gp = src + grow * lda + h * HROW + ((qchunk ^ (rloc & 7)) << 3);
      dma16(gp, wbase + q * (RPI * HROW));
    }
  };

  f16x8 bv0[4], bv1[4];
  #pragma unroll
  for (int nt = 0; nt < 4; ++nt) bv0[nt] = *(const f16x8*)(bp[nt]);
  #pragma unroll
  for (int nt = 0; nt < 4; ++nt) bv1[nt] = *(const f16x8*)(bp[nt] + 32);

  f32x4 acc[4][4];
  #pragma unroll
  for (int i = 0; i < 4; ++i)
    #pragma unroll
    for (int j = 0; j < 4; ++j) acc[i][j] = (f32x4){0.f, 0.f, 0.f, 0.f};

  auto compute_half = [&](const u16* buf, int l, int h) {
    #pragma unroll
    for (int kp = 0; kp < KCH; kp += 2) {
      const int gs = l * KC + h * KCH + kp;
      f16x8 a0[4], a1[4];
      #pragma unroll
      for (int mt = 0; mt < 4; ++mt) {
        int row = wm + mt * 16 + lr;
        a0[mt] = *(const f16x8*)(&buf[row * HROW + (((kp * 4 + lq) ^ (row & 7)) << 3)]);
      }
      #pragma unroll
      for (int mt = 0; mt < 4; ++mt) {
        int row = wm + mt * 16 + lr;
        a1[mt] = *(const f16x8*)(&buf[row * HROW + ((((kp + 1) * 4 + lq) ^ (row & 7)) << 3)]);
      }
      f16x8 t0[4];
      if (gs + 2 < TK) {
        #pragma unroll
        for (int nt = 0; nt < 4; ++nt) t0[nt] = *(const f16x8*)(bp[nt] + (long)(gs + 2) * 32);
      }
      #pragma unroll
      for (int mt = 0; mt < 4; ++mt)
        #pragma unroll
        for (int nt = 0; nt < 4; ++nt)
          acc[mt][nt] = __builtin_amdgcn_mfma_f32_16x16x32_f16(a0[mt], bv0[nt], acc[mt][nt], 0, 0, 0);
      f16x8 t1[4];
      if (gs + 3 < TK) {
        #pragma unroll
        for (int nt = 0; nt < 4; ++nt) t1[nt] = *(const f16x8*)(bp[nt] + (long)(gs + 3) * 32);
      }
      #pragma unroll
      for (int mt = 0; mt < 4; ++mt)
        #pragma unroll
        for (int nt = 0; nt < 4; ++nt)
          acc[mt][nt] = __builtin_amdgcn_mfma_f32_16x16x32_f16(a1[mt], bv1[nt], acc[mt][nt], 0, 0, 0);
      #pragma unroll
      for (int nt = 0; nt < 4; ++nt) { bv0[nt] = t0[nt]; bv1[nt] = t1[nt]; }
    }
  };

  // ---- prologue: idx for taps 0,1; DMA (tap0, h0) -> buf0 ----
  int idxC = gat ? load_idx(0) : 0;
  int idxN = (gat && L > 1) ? load_idx(1) : 0;
  dma_half(lA0, P0, idxC, 0);

  for (int l = 0; l < L; ++l) {
    const u16* sTap  = gat ? P0 : (l == 0 ? P0 : Pd1);   // source of tap l
    const u16* sTapN = gat ? P0 : Pd1;                   // source of tap l+1
    __syncthreads();                        // drains DMA for (l, h0) [issued last stage]
    dma_half(lA1, sTap, idxC, 1);           // (l, h1) -> buf1 (readers done pre-sync)
    compute_half(lA0, l, 0);
    __syncthreads();                        // drains DMA for (l, h1)
    if (l + 1 < L) dma_half(lA0, sTapN, idxN, 0);   // (l+1, h0) -> buf0
    compute_half(lA1, l, 1);
    idxC = idxN;
    if (gat && l + 2 < L) idxN = load_idx(l + 2);
  }

  // epilogue: C/D layout col=lane&15, row=(lane>>4)*4+reg [guide m89]; fused stats
  #pragma unroll
  for (int nt = 0; nt < 4; ++nt) {
    int col = wn + nt * 16 + lr;
    if (col < Ostore) {
      float bv = bias ? bias[col] : 0.f;
      float s1 = 0.f, s2 = 0.f;
      #pragma unroll
      for (int mt = 0; mt < 4; ++mt) {
        #pragma unroll
        for (int rg = 0; rg < 4; ++rg) {
          int row = bm + wm + mt * 16 + lq * 4 + rg;
          float v = acc[mt][nt][rg] + bv;
          Yb[(long)row * Ostore + col] = f2h(v);
          s1 += v; s2 += v * v;
        }
      }
      if (stats) {
        s1 += __shfl_xor(s1, 16); s1 += __shfl_xor(s1, 32);
        s2 += __shfl_xor(s2, 16); s2 += __shfl_xor(s2, 32);
        if (lq == 0) {
          atomicAdd(&stats[col], s1);
          atomicAdd(&stats[Ostore + col], s2);
        }
      }
    }
  }
}

// ---------- stats for enc0 output (O=256), vectorized ----------
__global__ __launch_bounds__(256) void stats2_k(const u16* __restrict__ y, float* __restrict__ st) {
  __shared__ float s1L[256], s2L[256];
  int tid = threadIdx.x;
  int ci = (tid & 63) * 4;
  int r0 = blockIdx.x * 64 + (tid >> 6);
  float a1[4] = {0,0,0,0}, a2[4] = {0,0,0,0};
  for (int it = 0; it < 16; ++it) {
    long i = ((long)r0 + it * 4) * 256 + ci;
    uint2 pv = *(const uint2*)(y + i);
    float v0 = h2f((u16)(pv.x & 0xffff)), v1 = h2f((u16)(pv.x >> 16));
    float v2 = h2f((u16)(pv.y & 0xffff)), v3 = h2f((u16)(pv.y >> 16));
    a1[0] += v0; a1[1] += v1; a1[2] += v2; a1[3] += v3;
    a2[0] += v0*v0; a2[1] += v1*v1; a2[2] += v2*v2; a2[3] += v3*v3;
  }
  s1L[tid] = 0.f; s2L[tid] = 0.f;
  __syncthreads();
  #pragma unroll
  for (int j = 0; j < 4; ++j) { atomicAdd(&s1L[ci + j], a1[j]); atomicAdd(&s2L[ci + j], a2[j]); }
  __syncthreads();
  atomicAdd(&st[tid], s1L[tid]);
  atomicAdd(&st[256 + tid], s2L[tid]);
}

// ---------- vectorized BN+ReLU (+fp16 residual, optional per-channel resid scale) (+SE sums) ----------
__global__ __launch_bounds__(256) void bnrelu2_k(
    const u16* __restrict__ y, const float* __restrict__ st,
    const float* __restrict__ g, const float* __restrict__ be,
    const u16* __restrict__ resid, const float* __restrict__ rscale,
    u16* __restrict__ ob, float* __restrict__ ses, int O)
{
  __shared__ float sL[256];
  int tid = threadIdx.x;
  int tpr = O >> 2;
  int rpi = 256 / tpr;
  int ci = (tid & (tpr - 1)) * 4;
  int row0 = blockIdx.x * (rpi * 16);
  int r0 = row0 + (tid / tpr);
  int b = row0 >> 14;
  float mean[4], sc[4], sh[4], rs[4];
  #pragma unroll
  for (int j = 0; j < 4; ++j) {
    int c = ci + j;
    float m = st[c] * (1.f / 32768.f);
    float var = st[O + c] * (1.f / 32768.f) - m * m;
    mean[j] = m;
    sc[j] = rsqrtf(fmaxf(var, 0.f) + 1e-5f) * g[c];
    sh[j] = be[c];
    rs[j] = rscale ? rscale[b * 256 + c] : 1.f;
  }
  float ss[4] = {0,0,0,0};
  for (int it = 0; it < 16; ++it) {
    long i = ((long)r0 + (long)it * rpi) * O + ci;
    uint2 pv = *(const uint2*)(y + i);
    float v[4];
    v[0] = fmaxf((h2f((u16)(pv.x & 0xffff)) - mean[0]) * sc[0] + sh[0], 0.f);
    v[1] = fmaxf((h2f((u16)(pv.x >> 16))    - mean[1]) * sc[1] + sh[1], 0.f);
    v[2] = fmaxf((h2f((u16)(pv.y & 0xffff)) - mean[2]) * sc[2] + sh[2], 0.f);
    v[3] = fmaxf((h2f((u16)(pv.y >> 16))    - mean[3]) * sc[3] + sh[3], 0.f);
    if (resid) {
      uint2 rv = *(const uint2*)(resid + i);
      v[0] += h2f((u16)(rv.x & 0xffff)) * rs[0]; v[1] += h2f((u16)(rv.x >> 16)) * rs[1];
      v[2] += h2f((u16)(rv.y & 0xffff)) * rs[2]; v[3] += h2f((u16)(rv.y >> 16)) * rs[3];
    }
    uint2 pk;
    pk.x = (unsigned)f2h(v[0]) | ((unsigned)f2h(v[1]) << 16);
    pk.y = (unsigned)f2h(v[2]) | ((unsigned)f2h(v[3]) << 16);
    *(uint2*)(ob + i) = pk;
    #pragma unroll
    for (int j = 0; j < 4; ++j) ss[j] += v[j];
  }
  if (ses) {
    sL[tid] = 0.f;
    __syncthreads();
    #pragma unroll
    for (int j = 0; j < 4; ++j) atomicAdd(&sL[ci + j], ss[j]);
    __syncthreads();
    atomicAdd(&ses[b * O + tid], sL[tid]);
  }
}

// ---------- SE gate ----------
__global__ void se_k(const float* __restrict__ ses, const float* __restrict__ w1,
                     const float* __restrict__ w2, float* __restrict__ sig)
{
  __shared__ float s[256];
  __shared__ float h[32];
  int b = blockIdx.x, t = threadIdx.x;
  s[t] = ses[b * 256 + t] * (1.f / 16384.f);
  __syncthreads();
  if (t < 32) {
    float a = 0.f;
    for (int c = 0; c < 256; ++c) a += w1[t * 256 + c] * s[c];
    h[t] = fmaxf(a, 0.f);
  }
  __syncthreads();
  float a = 0.f;
  #pragma unroll
  for (int r = 0; r < 32; ++r) a += w2[t * 32 + r] * h[r];
  sig[b * 256 + t] = 1.f / (1.f + expf(-a));
}

// ---------- x = out * sig (single use: decoder input materialization) ----------
__global__ __launch_bounds__(256) void scale_k(const u16* __restrict__ t, const float* __restrict__ sig,
                                               u16* __restrict__ xb)
{
  long i = ((long)blockIdx.x * 256 + threadIdx.x) * 4;
  int b = (int)(i >> 22);
  int c = (int)(i & 255);
  uint2 pv = *(const uint2*)(t + i);
  const float* sgp = sig + b * 256 + c;
  float v0 = h2f((u16)(pv.x & 0xffff)) * sgp[0];
  float v1 = h2f((u16)(pv.x >> 16))    * sgp[1];
  float v2 = h2f((u16)(pv.y & 0xffff)) * sgp[2];
  float v3 = h2f((u16)(pv.y >> 16))    * sgp[3];
  uint2 pk;
  pk.x = (unsigned)f2h(v0) | ((unsigned)f2h(v1) << 16);
  pk.y = (unsigned)f2h(v2) | ((unsigned)f2h(v3) << 16);
  *(uint2*)(xb + i) = pk;
}

// ---------- final head ----------
__global__ __launch_bounds__(256) void cls3_k(const u16* __restrict__ h2, const float* __restrict__ w,
                                              const float* __restrict__ b, float* __restrict__ out)
{
  __shared__ float ws[64];
  int t = threadIdx.x;
  if (t < 64) ws[t] = w[t];
  __syncthreads();
  int r = blockIdx.x * 256 + t;
  const u16* p = h2 + (long)r * 64;
  float a = b[0];
  #pragma unroll
  for (int c = 0; c < 64; ++c) a += ws[c] * h2f(p[c]);
  out[r] = a;
}

extern "C" void kernel_launch(void* const* d_in, const int* in_sizes, int n_in,
                              void* d_out, int out_size, void* d_ws, size_t ws_size,
                              hipStream_t stream)
{
  (void)in_sizes; (void)n_in; (void)out_size; (void)ws_size;
  const float* verts   = (const float*)d_in[0];
  const int*   spirals = (const int*)d_in[1];
  const float* enc0_w  = (const float*)d_in[2];
  const float* enc0_g  = (const float*)d_in[4];
  const float* enc0_be = (const float*)d_in[5];
  const float* enc_w   = (const float*)d_in[6];
  const float* enc_g   = (const float*)d_in[8];
  const float* enc_be  = (const float*)d_in[9];
  const float* se_w1   = (const float*)d_in[10];
  const float* se_w2   = (const float*)d_in[11];
  const float* skip_w  = (const float*)d_in[12];
  const float* skip_b  = (const float*)d_in[13];
  const float* dec_w   = (const float*)d_in[14];
  const float* dec_g   = (const float*)d_in[16];
  const float* dec_be  = (const float*)d_in[17];
  const float* cls1_w  = (const float*)d_in[18];
  const float* cls1_g  = (const float*)d_in[20];
  const float* cls1_be = (const float*)d_in[21];
  const float* cls2_w  = (const float*)d_in[22];
  const float* cls2_g  = (const float*)d_in[24];
  const float* cls2_be = (const float*)d_in[25];
  const float* cls3_w  = (const float*)d_in[26];
  const float* cls3_b  = (const float*)d_in[27];

  // --- workspace (~118 MB) ---
  char* p = (char*)d_ws;
  auto alloc = [&](size_t n) { char* q = p; p += (n + 255) & ~(size_t)255; return q; };
  u16* wpe     = (u16*)alloc((size_t)6 * 256 * 3072 * 2);       // 6 permuted conv weights
  u16* wpe_s   = (u16*)alloc((size_t)3 * 2 * 256 * 3072 * 2);   // enc, per-batch SE-folded
  u16* skip_wb = (u16*)alloc((size_t)3 * 256 * 512 * 2);
  u16* skip_s  = (u16*)alloc((size_t)3 * 2 * 256 * 512 * 2);    // skip, per-batch folded
  u16* cls1_wb = (u16*)alloc((size_t)256 * 256 * 2);            // zero-padded to 256 rows
  u16* wp6     = (u16*)alloc((size_t)256 * 128 * 2);            // zero-padded to 256 rows
  float* stats = (float*)alloc(2048);
  float* sesum = (float*)alloc(2048);                           // contiguous after stats
  float* sig   = (float*)alloc(4 * 2048);                       // sig_i = sig + i*512
  u16* out0 = (u16*)alloc((size_t)M_N * 256 * 2);
  u16* out1 = (u16*)alloc((size_t)M_N * 256 * 2);
  u16* out2 = (u16*)alloc((size_t)M_N * 256 * 2);
  u16* ct   = (u16*)alloc((size_t)M_N * 256 * 2);               // conv temp; aliases out3
  u16* tb   = (u16*)alloc((size_t)M_N * 256 * 2);
  u16* xd   = (u16*)alloc((size_t)M_N * 256 * 2);
  u16* outs[4] = {out0, out1, out2, ct};
  const size_t WENC = (size_t)256 * 3072;      // elems per enc weight copy
  const size_t WSKP = (size_t)256 * 512;

  // prep
  perm2_k<<<768, 256, 0, stream>>>(enc_w, wpe);
  perm2_k<<<768, 256, 0, stream>>>(dec_w, wpe + (size_t)3 * WENC);
  cvt_k<<<1536, 256, 0, stream>>>(skip_w, skip_wb, 3 * 256 * 512);
  hipMemsetAsync(cls1_wb, 0, 256 * 256 * 2, stream);
  cvt_k<<<128, 256, 0, stream>>>(cls1_w, cls1_wb, 128 * 256);
  hipMemsetAsync(wp6, 0, 256 * 128 * 2, stream);
  cvt_k<<<32, 256, 0, stream>>>(cls2_w, wp6, 64 * 128);

  // ---- encoder block 0 ----
  hipMemsetAsync(stats, 0, 4096, stream);
  enc0_k<<<1024, 256, 0, stream>>>(verts, spirals, enc0_w, ct);
  stats2_k<<<512, 256, 0, stream>>>(ct, stats);
  bnrelu2_k<<<512, 256, 0, stream>>>(ct, stats, enc0_g, enc0_be, nullptr, nullptr, out0, sesum, 256);
  se_k<<<2, 256, 0, stream>>>(sesum, se_w1, se_w2, sig);

  // ---- encoder blocks 1..3 (SE scale folded into per-batch weights) ----
  for (int i = 1; i < 4; ++i) {
    wscale_k<<<3072, 256, 0, stream>>>(wpe + (size_t)(i - 1) * WENC, sig + (i - 1) * 512,
                                       wpe_s + (size_t)(i - 1) * 2 * WENC, (int)WENC, 255);
    hipMemsetAsync(stats, 0, 4096, stream);
    gemm3_k<256><<<256, 512, 0, stream>>>(outs[i - 1], nullptr, 256,
                                          spirals + (size_t)i * V_N * 12, 12,
                                          wpe_s + (size_t)(i - 1) * 2 * WENC, (long)WENC,
                                          ct, nullptr, 256, stats);
    bnrelu2_k<<<512, 256, 0, stream>>>(ct, stats, enc_g + (i - 1) * 256, enc_be + (i - 1) * 256,
                                       outs[i - 1], sig + (i - 1) * 512, outs[i], sesum, 256);
    se_k<<<2, 256, 0, stream>>>(sesum, se_w1 + (size_t)i * 32 * 256,
                                se_w2 + (size_t)i * 256 * 32, sig + i * 512);
  }

  // decoder input x = out3 * sig3 (materialized once; out3 aliases ct)
  scale_k<<<8192, 256, 0, stream>>>(ct, sig + 3 * 512, xd);

  // ---- decoder blocks ----
  for (int i = 0; i < 3; ++i) {
    wscale_k<<<512, 256, 0, stream>>>(skip_wb + (size_t)i * WSKP, sig + (2 - i) * 512,
                                      skip_s + (size_t)i * 2 * WSKP, (int)WSKP, 511);
    gemm3_k<256><<<256, 512, 0, stream>>>(xd, outs[2 - i], 256, nullptr, 2,
                                          skip_s + (size_t)i * 2 * WSKP, (long)WSKP,
                                          tb, skip_b + i * 256, 256, nullptr);       // x1 -> tb
    hipMemsetAsync(stats, 0, 4096, stream);
    gemm3_k<256><<<256, 512, 0, stream>>>(tb, nullptr, 256,
                                          spirals + (size_t)(2 - i) * V_N * 12, 12,
                                          wpe + (size_t)(3 + i) * WENC, 0,
                                          outs[2 - i], nullptr, 256, stats);          // conv -> out[2-i]
    bnrelu2_k<<<512, 256, 0, stream>>>(outs[2 - i], stats, dec_g + i * 256, dec_be + i * 256,
                                       tb, nullptr, xd, nullptr, 256);                // x -> xd
  }

  // ---- classifier ----
  hipMemsetAsync(stats, 0, 4096, stream);
  gemm3_k<256><<<256, 512, 0, stream>>>(xd, nullptr, 256, nullptr, 1,
                                        cls1_wb, 0, ct, nullptr, 128, stats);
  bnrelu2_k<<<256, 256, 0, stream>>>(ct, stats, cls1_g, cls1_be, nullptr, nullptr, ct, nullptr, 128);
  hipMemsetAsync(stats, 0, 4096, stream);
  gemm3_k<128><<<256, 512, 0, stream>>>(ct, nullptr, 128, nullptr, 1,
                                        wp6, 0, tb, nullptr, 64, stats);
  bnrelu2_k<<<128, 256, 0, stream>>>(tb, stats, cls2_g, cls2_be, nullptr, nullptr, tb, nullptr, 64);
  cls3_k<<<128, 256, 0, stream>>>(tb, cls3_w, cls3_b, (float*)d_out);
}